// Round 1
// baseline (1053.923 us; speedup 1.0000x reference)
//
#include <hip/hip_runtime.h>
#include <math.h>

#define NQ      6400
#define NCAMS   6
#define LTOT    7979
#define DM      256
#define DFFN    1024

// ---------------------------------------------------------------------------
// Generic tiled fp32 GEMM: C[M,N] = A[M,K] @ B[K,N] + bias, optional relu.
// BM=BN=64, BK=16, 256 threads, 4x4 micro-tile. N %64==0, K %16==0; M guarded.
// ---------------------------------------------------------------------------
__global__ __launch_bounds__(256) void gemm_kernel(
    const float* __restrict__ A, const float* __restrict__ B,
    const float* __restrict__ bias, float* __restrict__ C,
    int M, int N, int K, int relu)
{
    __shared__ float As[16][65];   // [k][m] (transposed store)
    __shared__ float Bs[16][65];   // [k][n]
    const int tid = threadIdx.x;
    const int m0 = blockIdx.y * 64, n0 = blockIdx.x * 64;
    const int tx = tid & 15, ty = tid >> 4;
    float acc[4][4] = {};
    for (int k0 = 0; k0 < K; k0 += 16) {
        #pragma unroll
        for (int i = 0; i < 4; ++i) {
            int idx = tid + 256 * i;
            int r = idx >> 4, c = idx & 15;
            int gr = m0 + r;
            As[c][r] = (gr < M) ? A[(size_t)gr * K + k0 + c] : 0.f;
        }
        #pragma unroll
        for (int i = 0; i < 4; ++i) {
            int idx = tid + 256 * i;
            int r = idx >> 6, c = idx & 63;
            Bs[r][c] = B[(size_t)(k0 + r) * N + n0 + c];
        }
        __syncthreads();
        #pragma unroll
        for (int kk = 0; kk < 16; ++kk) {
            float a[4], b[4];
            #pragma unroll
            for (int r = 0; r < 4; ++r) a[r] = As[kk][ty * 4 + r];
            #pragma unroll
            for (int c = 0; c < 4; ++c) b[c] = Bs[kk][tx * 4 + c];
            #pragma unroll
            for (int r = 0; r < 4; ++r)
                #pragma unroll
                for (int c = 0; c < 4; ++c)
                    acc[r][c] += a[r] * b[c];
        }
        __syncthreads();
    }
    #pragma unroll
    for (int r = 0; r < 4; ++r) {
        int gm = m0 + ty * 4 + r;
        if (gm >= M) continue;
        #pragma unroll
        for (int c = 0; c < 4; ++c) {
            int gn = n0 + tx * 4 + c;
            float v = acc[r][c] + (bias ? bias[gn] : 0.f);
            if (relu) v = fmaxf(v, 0.f);
            C[(size_t)gm * N + gn] = v;
        }
    }
}

// ---------------------------------------------------------------------------
// In-place softmax over groups of 16 contiguous floats (per (query, head)).
// ---------------------------------------------------------------------------
__global__ void softmax16_kernel(float* __restrict__ p, int total)
{
    int t = blockIdx.x * blockDim.x + threadIdx.x;
    if (t >= total) return;
    float* q = p + (size_t)t * 16;
    float v[16], m = -1e30f;
    #pragma unroll
    for (int i = 0; i < 16; ++i) { v[i] = q[i]; m = fmaxf(m, v[i]); }
    float s = 0.f;
    #pragma unroll
    for (int i = 0; i < 16; ++i) { v[i] = expf(v[i] - m); s += v[i]; }
    float inv = 1.f / s;
    #pragma unroll
    for (int i = 0; i < 16; ++i) q[i] = v[i] * inv;
}

// ---------------------------------------------------------------------------
// Deformable sampling. One block per query. Loops over visible cameras.
// Threads 0..127 build corner idx/weight tables (one per (head,lvl,pt) tuple)
// in LDS; all 256 threads (head=tid>>5, ch=tid&31) gather-accumulate.
// Writes out_sum[n] = sum_vis(out_k)/max(nvis,1) and vis[n] = (nvis>0).
// ---------------------------------------------------------------------------
__global__ __launch_bounds__(256) void sample_kernel(
    const float* __restrict__ v,        // (6, 7979, 256)
    const float* __restrict__ qoff,     // (6400, 256)
    const float* __restrict__ aw,       // (6400, 128) softmaxed
    const float* __restrict__ refpts,   // (6, 1, 6400, 4, 2)
    const int*   __restrict__ bev_mask, // (6, 1, 6400, 4)
    float* __restrict__ out_sum,        // (6400, 256)
    float* __restrict__ visb)           // (6400)
{
    const int n = blockIdx.x;
    const int tid = threadIdx.x;
    const int h = tid >> 5, c = tid & 31;

    __shared__ int   s_idx[4][128];
    __shared__ float s_w[4][128];
    __shared__ int   s_mask[8];

    if (tid < NCAMS) {
        const int* bm = bev_mask + ((size_t)(tid * NQ) + n) * 4;
        s_mask[tid] = (bm[0] + bm[1] + bm[2] + bm[3]) > 0 ? 1 : 0;
    }
    __syncthreads();
    const int nvis = s_mask[0] + s_mask[1] + s_mask[2] + s_mask[3] + s_mask[4] + s_mask[5];

    // per-tuple camera-independent data
    float my_aw = 0.f, offx = 0.f, offy = 0.f;
    int lvl = 0;
    int Wl = 0, Hl = 0, base = 0;
    if (tid < 128) {
        lvl = (tid >> 2) & 3;
        my_aw = aw[(size_t)n * 128 + tid];
        offx = qoff[(size_t)n * 256 + 2 * tid];
        offy = qoff[(size_t)n * 256 + 2 * tid + 1];
        Wl   = (lvl == 0) ? 100 : (lvl == 1) ? 50 : (lvl == 2) ? 25 : 13;
        Hl   = (lvl == 0) ? 60  : (lvl == 1) ? 30 : (lvl == 2) ? 15 : 8;
        base = (lvl == 0) ? 0   : (lvl == 1) ? 6000 : (lvl == 2) ? 7500 : 7875;
    }

    float acc = 0.f;
    for (int k = 0; k < NCAMS; ++k) {
        if (!s_mask[k]) continue;
        if (tid < 128) {
            const size_t rbase = (((size_t)k * NQ + n) * 4 + lvl) * 2;
            float rx = refpts[rbase + 0];
            float ry = refpts[rbase + 1];
            float fx = (rx + offx / (float)Wl) * (float)Wl - 0.5f;
            float fy = (ry + offy / (float)Hl) * (float)Hl - 0.5f;
            float x0f = floorf(fx), y0f = floorf(fy);
            float lx = fx - x0f, ly = fy - y0f;
            int x0 = (int)x0f, y0 = (int)y0f;
            int x1 = x0 + 1, y1 = y0 + 1;
            float w00 = (1.f - lx) * (1.f - ly) * my_aw;
            float w01 = lx * (1.f - ly) * my_aw;
            float w10 = (1.f - lx) * ly * my_aw;
            float w11 = lx * ly * my_aw;
            bool vx0 = (x0 >= 0) & (x0 < Wl), vx1 = (x1 >= 0) & (x1 < Wl);
            bool vy0 = (y0 >= 0) & (y0 < Hl), vy1 = (y1 >= 0) & (y1 < Hl);
            s_idx[0][tid] = (vx0 & vy0) ? (base + y0 * Wl + x0) : -1; s_w[0][tid] = w00;
            s_idx[1][tid] = (vx1 & vy0) ? (base + y0 * Wl + x1) : -1; s_w[1][tid] = w01;
            s_idx[2][tid] = (vx0 & vy1) ? (base + y1 * Wl + x0) : -1; s_w[2][tid] = w10;
            s_idx[3][tid] = (vx1 & vy1) ? (base + y1 * Wl + x1) : -1; s_w[3][tid] = w11;
        }
        __syncthreads();
        const float* vk = v + (size_t)k * LTOT * 256 + (h << 5) + c;
        #pragma unroll
        for (int t16 = 0; t16 < 16; ++t16) {
            int tt = (h << 4) + t16;
            #pragma unroll
            for (int corner = 0; corner < 4; ++corner) {
                int idx = s_idx[corner][tt];
                float w = s_w[corner][tt];
                if (idx >= 0) acc += w * vk[(size_t)idx << 8];
            }
        }
        __syncthreads();
    }
    float scale = 1.f / (float)(nvis > 0 ? nvis : 1);
    out_sum[(size_t)n * 256 + tid] = acc * scale;
    if (tid == 0) visb[n] = (nvis > 0) ? 1.f : 0.f;
}

// ---------------------------------------------------------------------------
// Block reduction over 256 threads (4 waves of 64).
// ---------------------------------------------------------------------------
__device__ inline float block_sum_256(float v, float* red)
{
    #pragma unroll
    for (int o = 32; o > 0; o >>= 1) v += __shfl_down(v, o, 64);
    int lane = threadIdx.x & 63, w = threadIdx.x >> 6;
    if (lane == 0) red[w] = v;
    __syncthreads();
    float t = red[0] + red[1] + red[2] + red[3];
    __syncthreads();
    return t;
}

// LN1: x = LN( gemm_out + query*(1+vis) + vis*b_out )
__global__ __launch_bounds__(256) void ln1_kernel(
    const float* __restrict__ gin, const float* __restrict__ query,
    const float* __restrict__ visb, const float* __restrict__ b_out,
    const float* __restrict__ g, const float* __restrict__ b,
    float* __restrict__ xout)
{
    __shared__ float red[4];
    int n = blockIdx.x, j = threadIdx.x;
    float vs = visb[n];
    size_t idx = (size_t)n * 256 + j;
    float t = gin[idx] + query[idx] * (1.f + vs) + vs * b_out[j];
    float mu = block_sum_256(t, red) * (1.f / 256.f);
    float d = t - mu;
    float var = block_sum_256(d * d, red) * (1.f / 256.f);
    xout[idx] = d * rsqrtf(var + 1e-5f) * g[j] + b[j];
}

// LN2: out = LN( x + ffn )
__global__ __launch_bounds__(256) void ln2_kernel(
    const float* __restrict__ x, const float* __restrict__ ffn,
    const float* __restrict__ g, const float* __restrict__ b,
    float* __restrict__ out)
{
    __shared__ float red[4];
    int n = blockIdx.x, j = threadIdx.x;
    size_t idx = (size_t)n * 256 + j;
    float t = x[idx] + ffn[idx];
    float mu = block_sum_256(t, red) * (1.f / 256.f);
    float d = t - mu;
    float var = block_sum_256(d * d, red) * (1.f / 256.f);
    out[idx] = d * rsqrtf(var + 1e-5f) * g[j] + b[j];
}

// ---------------------------------------------------------------------------
extern "C" void kernel_launch(void* const* d_in, const int* in_sizes, int n_in,
                              void* d_out, int out_size, void* d_ws, size_t ws_size,
                              hipStream_t stream)
{
    const float* query   = (const float*)d_in[0];
    // d_in[1] = key (unused by reference)
    const float* value   = (const float*)d_in[2];
    const float* refpts  = (const float*)d_in[3];
    // d_in[4] spatial_shapes, d_in[5] level_start_index: hardcoded
    const int*   bevmask = (const int*)d_in[6];
    const float* W_value = (const float*)d_in[7];
    const float* b_value = (const float*)d_in[8];
    const float* W_off   = (const float*)d_in[9];
    const float* b_off   = (const float*)d_in[10];
    const float* W_attn  = (const float*)d_in[11];
    const float* b_attn  = (const float*)d_in[12];
    const float* W_out   = (const float*)d_in[13];
    const float* b_out   = (const float*)d_in[14];
    const float* ln1_g   = (const float*)d_in[15];
    const float* ln1_b   = (const float*)d_in[16];
    const float* W1      = (const float*)d_in[17];
    const float* b1      = (const float*)d_in[18];
    const float* W2      = (const float*)d_in[19];
    const float* b2      = (const float*)d_in[20];
    const float* ln2_g   = (const float*)d_in[21];
    const float* ln2_b   = (const float*)d_in[22];
    float* out = (float*)d_out;

    // workspace layout (bytes), with temporal aliasing:
    //   [0 .. 49,152,000)          v (K1..K3)  -> h (K5..K6) at offset 0
    //   [26,214,400 ..)            ln_in (K4..LN1), inside dead v region
    //   [49,152,000 ..)            qoff (K2..K3) -> ffnout (K6..LN2)
    //   [55,705,600 ..)            aw logits/softmax (K2..K3)
    //   [58,982,400 ..)            out_sum (K3..K4) -> x (LN1..LN2)
    //   [65,536,000 ..)            vis flags
    char* ws = (char*)d_ws;
    float* v      = (float*)(ws + 0);
    float* h_ffn  = (float*)(ws + 0);
    float* ln_in  = (float*)(ws + 26214400);
    float* qoff   = (float*)(ws + 49152000);
    float* ffnout = (float*)(ws + 49152000);
    float* qaw    = (float*)(ws + 55705600);
    float* outsum = (float*)(ws + 58982400);
    float* xbuf   = (float*)(ws + 58982400);
    float* visb   = (float*)(ws + 65536000);

    const int MV = NCAMS * LTOT;  // 47874

    // K1: v = value @ W_value + b_value   (47874 x 256 x 256)
    gemm_kernel<<<dim3(4, (MV + 63) / 64), 256, 0, stream>>>(
        value, W_value, b_value, v, MV, 256, 256, 0);
    // K2a: qoff = query @ W_off + b_off   (6400 x 256 x 256)
    gemm_kernel<<<dim3(4, 100), 256, 0, stream>>>(
        query, W_off, b_off, qoff, NQ, 256, 256, 0);
    // K2b: logits = query @ W_attn + b_attn (6400 x 128 x 256)
    gemm_kernel<<<dim3(2, 100), 256, 0, stream>>>(
        query, W_attn, b_attn, qaw, NQ, 128, 256, 0);
    // K2c: softmax over 16 per (query, head)
    softmax16_kernel<<<dim3((NQ * 8 + 255) / 256), 256, 0, stream>>>(qaw, NQ * 8);
    // K3: deformable sampling + camera sum + 1/count scaling
    sample_kernel<<<dim3(NQ), 256, 0, stream>>>(
        v, qoff, qaw, refpts, bevmask, outsum, visb);
    // K4: ln_in = outsum @ W_out          (6400 x 256 x 256, no bias)
    gemm_kernel<<<dim3(4, 100), 256, 0, stream>>>(
        outsum, W_out, nullptr, ln_in, NQ, 256, 256, 0);
    // LN1 (fused residual algebra)
    ln1_kernel<<<dim3(NQ), 256, 0, stream>>>(
        ln_in, query, visb, b_out, ln1_g, ln1_b, xbuf);
    // K5: h = relu(x @ W1 + b1)           (6400 x 1024 x 256)
    gemm_kernel<<<dim3(16, 100), 256, 0, stream>>>(
        xbuf, W1, b1, h_ffn, NQ, DFFN, 256, 1);
    // K6: ffnout = h @ W2 + b2            (6400 x 256 x 1024)
    gemm_kernel<<<dim3(4, 100), 256, 0, stream>>>(
        h_ffn, W2, b2, ffnout, NQ, 256, DFFN, 0);
    // LN2 -> output
    ln2_kernel<<<dim3(NQ), 256, 0, stream>>>(
        xbuf, ffnout, ln2_g, ln2_b, out);
}

// Round 2
// 858.845 us; speedup vs baseline: 1.2271x; 1.2271x over previous
//
#include <hip/hip_runtime.h>
#include <math.h>

#define NQ      6400
#define NCAMS   6
#define LTOT    7979
#define DM      256
#define DFFN    1024

__device__ inline unsigned short f32_to_bf16(float f) {
    unsigned u = __float_as_uint(f);
    unsigned r = u + 0x7FFF + ((u >> 16) & 1);   // round-to-nearest-even
    return (unsigned short)(r >> 16);
}

// ---------------------------------------------------------------------------
// Tiled fp32 GEMM: C[M,N] = A[M,K] @ B[K,N] + bias.
// mode 0: fp32 out; mode 1: fp32 relu out; mode 2: bf16 out in head-major
//         v-layout (cam, head, pixel, 32ch), m = cam*LTOT+pixel, n = head*32+ch.
// BM=BN=64, BK=16, 256 threads, 4x4 micro-tile. N%64==0, K%16==0; M guarded.
// ---------------------------------------------------------------------------
__global__ __launch_bounds__(256) void gemm_kernel(
    const float* __restrict__ A, const float* __restrict__ B,
    const float* __restrict__ bias, float* __restrict__ C,
    unsigned short* __restrict__ Cb,
    int M, int N, int K, int mode)
{
    __shared__ float As[16][65];   // [k][m]
    __shared__ float Bs[16][65];   // [k][n]
    const int tid = threadIdx.x;
    const int m0 = blockIdx.y * 64, n0 = blockIdx.x * 64;
    const int tx = tid & 15, ty = tid >> 4;
    float acc[4][4] = {};
    for (int k0 = 0; k0 < K; k0 += 16) {
        #pragma unroll
        for (int i = 0; i < 4; ++i) {
            int idx = tid + 256 * i;
            int r = idx >> 4, c = idx & 15;
            int gr = m0 + r;
            As[c][r] = (gr < M) ? A[(size_t)gr * K + k0 + c] : 0.f;
        }
        #pragma unroll
        for (int i = 0; i < 4; ++i) {
            int idx = tid + 256 * i;
            int r = idx >> 6, c = idx & 63;
            Bs[r][c] = B[(size_t)(k0 + r) * N + n0 + c];
        }
        __syncthreads();
        #pragma unroll
        for (int kk = 0; kk < 16; ++kk) {
            float a[4], b[4];
            #pragma unroll
            for (int r = 0; r < 4; ++r) a[r] = As[kk][ty * 4 + r];
            #pragma unroll
            for (int c = 0; c < 4; ++c) b[c] = Bs[kk][tx * 4 + c];
            #pragma unroll
            for (int r = 0; r < 4; ++r)
                #pragma unroll
                for (int c = 0; c < 4; ++c)
                    acc[r][c] += a[r] * b[c];
        }
        __syncthreads();
    }
    if (mode == 2) {
        #pragma unroll
        for (int r = 0; r < 4; ++r) {
            int gm = m0 + ty * 4 + r;
            if (gm >= M) continue;
            int cam = gm / LTOT;
            int pix = gm - cam * LTOT;
            #pragma unroll
            for (int c = 0; c < 4; ++c) {
                int gn = n0 + tx * 4 + c;
                int head = gn >> 5, ch = gn & 31;
                float v = acc[r][c] + bias[gn];
                Cb[(((size_t)(cam * 8 + head)) * LTOT + pix) * 32 + ch] = f32_to_bf16(v);
            }
        }
    } else {
        #pragma unroll
        for (int r = 0; r < 4; ++r) {
            int gm = m0 + ty * 4 + r;
            if (gm >= M) continue;
            #pragma unroll
            for (int c = 0; c < 4; ++c) {
                int gn = n0 + tx * 4 + c;
                float v = acc[r][c] + (bias ? bias[gn] : 0.f);
                if (mode == 1) v = fmaxf(v, 0.f);
                C[(size_t)gm * N + gn] = v;
            }
        }
    }
}

// ---------------------------------------------------------------------------
// In-place softmax over groups of 16 contiguous floats (per (query, head)).
// ---------------------------------------------------------------------------
__global__ void softmax16_kernel(float* __restrict__ p, int total)
{
    int t = blockIdx.x * blockDim.x + threadIdx.x;
    if (t >= total) return;
    float* q = p + (size_t)t * 16;
    float v[16], m = -1e30f;
    #pragma unroll
    for (int i = 0; i < 16; ++i) { v[i] = q[i]; m = fmaxf(m, v[i]); }
    float s = 0.f;
    #pragma unroll
    for (int i = 0; i < 16; ++i) { v[i] = expf(v[i] - m); s += v[i]; }
    float inv = 1.f / s;
    #pragma unroll
    for (int i = 0; i < 16; ++i) q[i] = v[i] * inv;
}

// ---------------------------------------------------------------------------
// Deformable sampling, bf16 head-major v: (cam, head, pixel, 32ch) ushort.
// One block per query. Thread map: p = tid>>7 (tuple parity), h = (tid>>4)&7,
// c2 = tid&15 (2 channels). Each thread owns channels (h, 2c2, 2c2+1) and
// accumulates tuples tt = h*16 + it*2 + p over it=0..7 and 4 corners.
// Pair (p=0/1) partials reduced through LDS at the end.
// ---------------------------------------------------------------------------
__global__ __launch_bounds__(256) void sample_kernel(
    const unsigned short* __restrict__ vb, // (6, 8, 7979, 32) bf16
    const float* __restrict__ qoff,        // (6400, 256)
    const float* __restrict__ aw,          // (6400, 128) softmaxed
    const float* __restrict__ refpts,      // (6, 1, 6400, 4, 2)
    const int*   __restrict__ bev_mask,    // (6, 1, 6400, 4)
    float* __restrict__ out_sum,           // (6400, 256)
    float* __restrict__ visb)              // (6400)
{
    const int n = blockIdx.x;
    const int tid = threadIdx.x;
    const int p  = tid >> 7;
    const int h  = (tid >> 4) & 7;
    const int c2 = tid & 15;

    __shared__ int   s_idx[4][128];
    __shared__ float s_w[4][128];
    __shared__ int   s_mask[8];
    __shared__ float s_red[256][2];

    if (tid < NCAMS) {
        const int* bm = bev_mask + ((size_t)(tid * NQ) + n) * 4;
        s_mask[tid] = (bm[0] + bm[1] + bm[2] + bm[3]) > 0 ? 1 : 0;
    }
    __syncthreads();
    const int nvis = s_mask[0] + s_mask[1] + s_mask[2] + s_mask[3] + s_mask[4] + s_mask[5];

    // per-tuple camera-independent data (tid<128 builds the corner tables)
    float my_aw = 0.f, dx = 0.f, dy = 0.f;
    int lvl = 0, Wl = 0, Hl = 0, base = 0;
    if (tid < 128) {
        lvl = (tid >> 2) & 3;
        my_aw = aw[(size_t)n * 128 + tid];
        float offx = qoff[(size_t)n * 256 + 2 * tid];
        float offy = qoff[(size_t)n * 256 + 2 * tid + 1];
        Wl   = (lvl == 0) ? 100 : (lvl == 1) ? 50 : (lvl == 2) ? 25 : 13;
        Hl   = (lvl == 0) ? 60  : (lvl == 1) ? 30 : (lvl == 2) ? 15 : 8;
        base = (lvl == 0) ? 0   : (lvl == 1) ? 6000 : (lvl == 2) ? 7500 : 7875;
        dx = offx / (float)Wl;
        dy = offy / (float)Hl;
    }

    float acc0 = 0.f, acc1 = 0.f;
    for (int k = 0; k < NCAMS; ++k) {
        if (!s_mask[k]) continue;
        if (tid < 128) {
            const size_t rbase = (((size_t)k * NQ + n) * 4 + lvl) * 2;
            float fx = (refpts[rbase + 0] + dx) * (float)Wl - 0.5f;
            float fy = (refpts[rbase + 1] + dy) * (float)Hl - 0.5f;
            float x0f = floorf(fx), y0f = floorf(fy);
            float lx = fx - x0f, ly = fy - y0f;
            int x0 = (int)x0f, y0 = (int)y0f;
            int x1 = x0 + 1, y1 = y0 + 1;
            float w00 = (1.f - lx) * (1.f - ly) * my_aw;
            float w01 = lx * (1.f - ly) * my_aw;
            float w10 = (1.f - lx) * ly * my_aw;
            float w11 = lx * ly * my_aw;
            bool vx0 = (x0 >= 0) & (x0 < Wl), vx1 = (x1 >= 0) & (x1 < Wl);
            bool vy0 = (y0 >= 0) & (y0 < Hl), vy1 = (y1 >= 0) & (y1 < Hl);
            s_idx[0][tid] = (vx0 & vy0) ? (base + y0 * Wl + x0) : -1; s_w[0][tid] = w00;
            s_idx[1][tid] = (vx1 & vy0) ? (base + y0 * Wl + x1) : -1; s_w[1][tid] = w01;
            s_idx[2][tid] = (vx0 & vy1) ? (base + y1 * Wl + x0) : -1; s_w[2][tid] = w10;
            s_idx[3][tid] = (vx1 & vy1) ? (base + y1 * Wl + x1) : -1; s_w[3][tid] = w11;
        }
        __syncthreads();
        // base pointer for (cam k, head h), channel pair c2
        const unsigned short* vkh = vb + ((size_t)(k * 8 + h) * LTOT) * 32 + c2 * 2;
        #pragma unroll
        for (int it = 0; it < 8; ++it) {
            int tt = (h << 4) + (it << 1) + p;
            #pragma unroll
            for (int corner = 0; corner < 4; ++corner) {
                int idx = s_idx[corner][tt];
                float w = s_w[corner][tt];
                if (idx >= 0) {
                    unsigned u = *(const unsigned*)(vkh + idx * 32);
                    float f0 = __uint_as_float((u & 0xFFFFu) << 16);
                    float f1 = __uint_as_float(u & 0xFFFF0000u);
                    acc0 += w * f0;
                    acc1 += w * f1;
                }
            }
        }
        __syncthreads();
    }

    s_red[tid][0] = acc0;
    s_red[tid][1] = acc1;
    __syncthreads();
    if (tid < 128) {
        float scale = 1.f / (float)(nvis > 0 ? nvis : 1);
        float a0 = (s_red[tid][0] + s_red[tid + 128][0]) * scale;
        float a1 = (s_red[tid][1] + s_red[tid + 128][1]) * scale;
        int hh = tid >> 4, cc = tid & 15;
        out_sum[(size_t)n * 256 + hh * 32 + cc * 2]     = a0;
        out_sum[(size_t)n * 256 + hh * 32 + cc * 2 + 1] = a1;
    }
    if (tid == 0) visb[n] = (nvis > 0) ? 1.f : 0.f;
}

// ---------------------------------------------------------------------------
// Block reduction over 256 threads (4 waves of 64).
// ---------------------------------------------------------------------------
__device__ inline float block_sum_256(float v, float* red)
{
    #pragma unroll
    for (int o = 32; o > 0; o >>= 1) v += __shfl_down(v, o, 64);
    int lane = threadIdx.x & 63, w = threadIdx.x >> 6;
    if (lane == 0) red[w] = v;
    __syncthreads();
    float t = red[0] + red[1] + red[2] + red[3];
    __syncthreads();
    return t;
}

// LN1: x = LN( gemm_out + query*(1+vis) + vis*b_out )
__global__ __launch_bounds__(256) void ln1_kernel(
    const float* __restrict__ gin, const float* __restrict__ query,
    const float* __restrict__ visb, const float* __restrict__ b_out,
    const float* __restrict__ g, const float* __restrict__ b,
    float* __restrict__ xout)
{
    __shared__ float red[4];
    int n = blockIdx.x, j = threadIdx.x;
    float vs = visb[n];
    size_t idx = (size_t)n * 256 + j;
    float t = gin[idx] + query[idx] * (1.f + vs) + vs * b_out[j];
    float mu = block_sum_256(t, red) * (1.f / 256.f);
    float d = t - mu;
    float var = block_sum_256(d * d, red) * (1.f / 256.f);
    xout[idx] = d * rsqrtf(var + 1e-5f) * g[j] + b[j];
}

// LN2: out = LN( x + ffn )
__global__ __launch_bounds__(256) void ln2_kernel(
    const float* __restrict__ x, const float* __restrict__ ffn,
    const float* __restrict__ g, const float* __restrict__ b,
    float* __restrict__ out)
{
    __shared__ float red[4];
    int n = blockIdx.x, j = threadIdx.x;
    size_t idx = (size_t)n * 256 + j;
    float t = x[idx] + ffn[idx];
    float mu = block_sum_256(t, red) * (1.f / 256.f);
    float d = t - mu;
    float var = block_sum_256(d * d, red) * (1.f / 256.f);
    out[idx] = d * rsqrtf(var + 1e-5f) * g[j] + b[j];
}

// ---------------------------------------------------------------------------
extern "C" void kernel_launch(void* const* d_in, const int* in_sizes, int n_in,
                              void* d_out, int out_size, void* d_ws, size_t ws_size,
                              hipStream_t stream)
{
    const float* query   = (const float*)d_in[0];
    const float* value   = (const float*)d_in[2];
    const float* refpts  = (const float*)d_in[3];
    const int*   bevmask = (const int*)d_in[6];
    const float* W_value = (const float*)d_in[7];
    const float* b_value = (const float*)d_in[8];
    const float* W_off   = (const float*)d_in[9];
    const float* b_off   = (const float*)d_in[10];
    const float* W_attn  = (const float*)d_in[11];
    const float* b_attn  = (const float*)d_in[12];
    const float* W_out   = (const float*)d_in[13];
    const float* b_out   = (const float*)d_in[14];
    const float* ln1_g   = (const float*)d_in[15];
    const float* ln1_b   = (const float*)d_in[16];
    const float* W1      = (const float*)d_in[17];
    const float* b1      = (const float*)d_in[18];
    const float* W2      = (const float*)d_in[19];
    const float* b2      = (const float*)d_in[20];
    const float* ln2_g   = (const float*)d_in[21];
    const float* ln2_b   = (const float*)d_in[22];
    float* out = (float*)d_out;

    // workspace layout (bytes), temporal aliasing:
    //   [0 .. 24,511,488)   v_bf16 (K1..K3)  -> h_ffn (K5..K6) at offset 0
    //   [26,214,400 ..)     ln_in (K4..LN1)
    //   [49,152,000 ..)     qoff (K2..K3) -> ffnout (K6..LN2)
    //   [55,705,600 ..)     aw logits/softmax (K2..K3)
    //   [58,982,400 ..)     out_sum (K3..K4) -> x (LN1..LN2)
    //   [65,536,000 ..)     vis flags
    char* ws = (char*)d_ws;
    unsigned short* vb = (unsigned short*)(ws + 0);
    float* h_ffn  = (float*)(ws + 0);
    float* ln_in  = (float*)(ws + 26214400);
    float* qoff   = (float*)(ws + 49152000);
    float* ffnout = (float*)(ws + 49152000);
    float* qaw    = (float*)(ws + 55705600);
    float* outsum = (float*)(ws + 58982400);
    float* xbuf   = (float*)(ws + 58982400);
    float* visb   = (float*)(ws + 65536000);

    const int MV = NCAMS * LTOT;  // 47874

    // K1: v = value @ W_value + b_value  -> bf16 head-major layout
    gemm_kernel<<<dim3(4, (MV + 63) / 64), 256, 0, stream>>>(
        value, W_value, b_value, nullptr, vb, MV, 256, 256, 2);
    // K2a: qoff = query @ W_off + b_off
    gemm_kernel<<<dim3(4, 100), 256, 0, stream>>>(
        query, W_off, b_off, qoff, nullptr, NQ, 256, 256, 0);
    // K2b: logits = query @ W_attn + b_attn
    gemm_kernel<<<dim3(2, 100), 256, 0, stream>>>(
        query, W_attn, b_attn, qaw, nullptr, NQ, 128, 256, 0);
    // K2c: softmax over 16 per (query, head)
    softmax16_kernel<<<dim3((NQ * 8 + 255) / 256), 256, 0, stream>>>(qaw, NQ * 8);
    // K3: deformable sampling + camera sum + 1/count scaling
    sample_kernel<<<dim3(NQ), 256, 0, stream>>>(
        vb, qoff, qaw, refpts, bevmask, outsum, visb);
    // K4: ln_in = outsum @ W_out (no bias)
    gemm_kernel<<<dim3(4, 100), 256, 0, stream>>>(
        outsum, W_out, nullptr, ln_in, nullptr, NQ, 256, 256, 0);
    // LN1 (fused residual algebra)
    ln1_kernel<<<dim3(NQ), 256, 0, stream>>>(
        ln_in, query, visb, b_out, ln1_g, ln1_b, xbuf);
    // K5: h = relu(x @ W1 + b1)
    gemm_kernel<<<dim3(16, 100), 256, 0, stream>>>(
        xbuf, W1, b1, h_ffn, nullptr, NQ, DFFN, 256, 1);
    // K6: ffnout = h @ W2 + b2
    gemm_kernel<<<dim3(4, 100), 256, 0, stream>>>(
        h_ffn, W2, b2, ffnout, nullptr, NQ, 256, DFFN, 0);
    // LN2 -> output
    ln2_kernel<<<dim3(NQ), 256, 0, stream>>>(
        xbuf, ffnout, ln2_g, ln2_b, out);
}

// Round 3
// 667.351 us; speedup vs baseline: 1.5793x; 1.2869x over previous
//
#include <hip/hip_runtime.h>
#include <math.h>

#define NQ      6400
#define NCAMS   6
#define LTOT    7979
#define DM      256
#define DFFN    1024

typedef __attribute__((ext_vector_type(8))) short bf16x8;
typedef __attribute__((ext_vector_type(4))) float f32x4;

__device__ inline unsigned short f32_to_bf16(float f) {
    unsigned u = __float_as_uint(f);
    unsigned r = u + 0x7FFF + ((u >> 16) & 1);   // round-to-nearest-even
    return (unsigned short)(r >> 16);
}

// ---------------------------------------------------------------------------
// MFMA bf16 GEMM: C[M,N] = A[M,K] @ B[K,N] + bias (A,B fp32 in global,
// converted to bf16 while staging to LDS; fp32 accumulate).
// BM=BN=128, BK=32, 256 threads = 4 waves in 2x2, each wave 64x64 via
// 4x4 grid of 16x16x32 MFMA. N%128==0, K%32==0; M guarded.
// mode 0: fp32 out (+bias if non-null); 1: fp32 relu; 2: bf16 head-major
//         v-layout (cam, head, pixel, 32ch) for the value projection.
// ---------------------------------------------------------------------------
__global__ __launch_bounds__(256) void mfma_gemm(
    const float* __restrict__ A, const float* __restrict__ B,
    const float* __restrict__ bias, float* __restrict__ C,
    unsigned short* __restrict__ Cb,
    int M, int N, int K, int mode)
{
    __shared__ __align__(16) unsigned short As[128][40];  // [m][k], pad 32->40
    __shared__ __align__(16) unsigned short Bs[128][40];  // [n][k], pad 32->40

    const int tid  = threadIdx.x;
    const int wave = tid >> 6, lane = tid & 63;
    const int wm = wave >> 1, wn = wave & 1;
    const int quad = lane >> 4, l16 = lane & 15;
    const int m0 = blockIdx.y * 128, n0 = blockIdx.x * 128;

    f32x4 acc[4][4] = {};

    for (int k0 = 0; k0 < K; k0 += 32) {
        // stage A tile (128 x 32): 1024 float4 chunks, 4 per thread
        #pragma unroll
        for (int i = 0; i < 4; ++i) {
            int idx = tid + 256 * i;
            int r = idx >> 3;            // 0..127
            int kc = (idx & 7) * 4;      // 0..28
            int gr = m0 + r;
            float4 f = (gr < M) ? *(const float4*)(A + (size_t)gr * K + k0 + kc)
                                : make_float4(0.f, 0.f, 0.f, 0.f);
            unsigned short* dst = &As[r][kc];
            dst[0] = f32_to_bf16(f.x); dst[1] = f32_to_bf16(f.y);
            dst[2] = f32_to_bf16(f.z); dst[3] = f32_to_bf16(f.w);
        }
        // stage B tile (32 x 128) transposed into Bs[n][k]
        #pragma unroll
        for (int i = 0; i < 4; ++i) {
            int idx = tid + 256 * i;
            int kr = idx >> 5;           // 0..31
            int c  = (idx & 31) * 4;     // 0..124
            float4 f = *(const float4*)(B + (size_t)(k0 + kr) * N + n0 + c);
            Bs[c    ][kr] = f32_to_bf16(f.x);
            Bs[c + 1][kr] = f32_to_bf16(f.y);
            Bs[c + 2][kr] = f32_to_bf16(f.z);
            Bs[c + 3][kr] = f32_to_bf16(f.w);
        }
        __syncthreads();

        bf16x8 af[4], bfr[4];
        #pragma unroll
        for (int mi = 0; mi < 4; ++mi)
            af[mi] = *(const bf16x8*)&As[wm * 64 + mi * 16 + l16][quad * 8];
        #pragma unroll
        for (int ni = 0; ni < 4; ++ni)
            bfr[ni] = *(const bf16x8*)&Bs[wn * 64 + ni * 16 + l16][quad * 8];
        #pragma unroll
        for (int mi = 0; mi < 4; ++mi)
            #pragma unroll
            for (int ni = 0; ni < 4; ++ni)
                acc[mi][ni] = __builtin_amdgcn_mfma_f32_16x16x32_bf16(
                    af[mi], bfr[ni], acc[mi][ni], 0, 0, 0);
        __syncthreads();
    }

    // epilogue: D[m0 + wm*64 + mi*16 + quad*4 + r][n0 + wn*64 + ni*16 + l16]
    if (mode == 2) {
        #pragma unroll
        for (int mi = 0; mi < 4; ++mi) {
            #pragma unroll
            for (int r = 0; r < 4; ++r) {
                int gm = m0 + wm * 64 + mi * 16 + quad * 4 + r;
                if (gm >= M) continue;
                int cam = gm / LTOT;
                int pix = gm - cam * LTOT;
                #pragma unroll
                for (int ni = 0; ni < 4; ++ni) {
                    int gn = n0 + wn * 64 + ni * 16 + l16;
                    int head = gn >> 5, ch = gn & 31;
                    float v = acc[mi][ni][r] + bias[gn];
                    Cb[(((size_t)(cam * 8 + head)) * LTOT + pix) * 32 + ch] = f32_to_bf16(v);
                }
            }
        }
    } else {
        #pragma unroll
        for (int mi = 0; mi < 4; ++mi) {
            #pragma unroll
            for (int r = 0; r < 4; ++r) {
                int gm = m0 + wm * 64 + mi * 16 + quad * 4 + r;
                if (gm >= M) continue;
                #pragma unroll
                for (int ni = 0; ni < 4; ++ni) {
                    int gn = n0 + wn * 64 + ni * 16 + l16;
                    float v = acc[mi][ni][r] + (bias ? bias[gn] : 0.f);
                    if (mode == 1) v = fmaxf(v, 0.f);
                    C[(size_t)gm * N + gn] = v;
                }
            }
        }
    }
}

// ---------------------------------------------------------------------------
// In-place softmax over groups of 16 contiguous floats (per (query, head)).
// ---------------------------------------------------------------------------
__global__ void softmax16_kernel(float* __restrict__ p, int total)
{
    int t = blockIdx.x * blockDim.x + threadIdx.x;
    if (t >= total) return;
    float* q = p + (size_t)t * 16;
    float v[16], m = -1e30f;
    #pragma unroll
    for (int i = 0; i < 16; ++i) { v[i] = q[i]; m = fmaxf(m, v[i]); }
    float s = 0.f;
    #pragma unroll
    for (int i = 0; i < 16; ++i) { v[i] = expf(v[i] - m); s += v[i]; }
    float inv = 1.f / s;
    #pragma unroll
    for (int i = 0; i < 16; ++i) q[i] = v[i] * inv;
}

// ---------------------------------------------------------------------------
// Deformable sampling, bf16 head-major v: (cam, head, pixel, 32ch) ushort.
// One block per query, XCD-swizzled: n = (bid&7)*800 + bid>>3 so each XCD
// owns a contiguous (spatially local) query range for L2 reuse.
// ---------------------------------------------------------------------------
__global__ __launch_bounds__(256) void sample_kernel(
    const unsigned short* __restrict__ vb, // (6, 8, 7979, 32) bf16
    const float* __restrict__ qoff,        // (6400, 256)
    const float* __restrict__ aw,          // (6400, 128) softmaxed
    const float* __restrict__ refpts,      // (6, 1, 6400, 4, 2)
    const int*   __restrict__ bev_mask,    // (6, 1, 6400, 4)
    float* __restrict__ out_sum,           // (6400, 256)
    float* __restrict__ visb)              // (6400)
{
    const int bid = blockIdx.x;
    const int n = (bid & 7) * 800 + (bid >> 3);   // XCD-aware swizzle
    const int tid = threadIdx.x;
    const int p  = tid >> 7;
    const int h  = (tid >> 4) & 7;
    const int c2 = tid & 15;

    __shared__ int   s_idx[4][128];
    __shared__ float s_w[4][128];
    __shared__ int   s_mask[8];
    __shared__ float s_red[256][2];

    if (tid < NCAMS) {
        const int* bm = bev_mask + ((size_t)(tid * NQ) + n) * 4;
        s_mask[tid] = (bm[0] + bm[1] + bm[2] + bm[3]) > 0 ? 1 : 0;
    }
    __syncthreads();
    const int nvis = s_mask[0] + s_mask[1] + s_mask[2] + s_mask[3] + s_mask[4] + s_mask[5];

    float my_aw = 0.f, dx = 0.f, dy = 0.f;
    int lvl = 0, Wl = 0, Hl = 0, base = 0;
    if (tid < 128) {
        lvl = (tid >> 2) & 3;
        my_aw = aw[(size_t)n * 128 + tid];
        float offx = qoff[(size_t)n * 256 + 2 * tid];
        float offy = qoff[(size_t)n * 256 + 2 * tid + 1];
        Wl   = (lvl == 0) ? 100 : (lvl == 1) ? 50 : (lvl == 2) ? 25 : 13;
        Hl   = (lvl == 0) ? 60  : (lvl == 1) ? 30 : (lvl == 2) ? 15 : 8;
        base = (lvl == 0) ? 0   : (lvl == 1) ? 6000 : (lvl == 2) ? 7500 : 7875;
        dx = offx / (float)Wl;
        dy = offy / (float)Hl;
    }

    float acc0 = 0.f, acc1 = 0.f;
    for (int k = 0; k < NCAMS; ++k) {
        if (!s_mask[k]) continue;
        if (tid < 128) {
            const size_t rbase = (((size_t)k * NQ + n) * 4 + lvl) * 2;
            float fx = (refpts[rbase + 0] + dx) * (float)Wl - 0.5f;
            float fy = (refpts[rbase + 1] + dy) * (float)Hl - 0.5f;
            float x0f = floorf(fx), y0f = floorf(fy);
            float lx = fx - x0f, ly = fy - y0f;
            int x0 = (int)x0f, y0 = (int)y0f;
            int x1 = x0 + 1, y1 = y0 + 1;
            float w00 = (1.f - lx) * (1.f - ly) * my_aw;
            float w01 = lx * (1.f - ly) * my_aw;
            float w10 = (1.f - lx) * ly * my_aw;
            float w11 = lx * ly * my_aw;
            bool vx0 = (x0 >= 0) & (x0 < Wl), vx1 = (x1 >= 0) & (x1 < Wl);
            bool vy0 = (y0 >= 0) & (y0 < Hl), vy1 = (y1 >= 0) & (y1 < Hl);
            s_idx[0][tid] = (vx0 & vy0) ? (base + y0 * Wl + x0) : -1; s_w[0][tid] = w00;
            s_idx[1][tid] = (vx1 & vy0) ? (base + y0 * Wl + x1) : -1; s_w[1][tid] = w01;
            s_idx[2][tid] = (vx0 & vy1) ? (base + y1 * Wl + x0) : -1; s_w[2][tid] = w10;
            s_idx[3][tid] = (vx1 & vy1) ? (base + y1 * Wl + x1) : -1; s_w[3][tid] = w11;
        }
        __syncthreads();
        const unsigned short* vkh = vb + ((size_t)(k * 8 + h) * LTOT) * 32 + c2 * 2;
        #pragma unroll
        for (int it = 0; it < 8; ++it) {
            int tt = (h << 4) + (it << 1) + p;
            #pragma unroll
            for (int corner = 0; corner < 4; ++corner) {
                int idx = s_idx[corner][tt];
                float w = s_w[corner][tt];
                if (idx >= 0) {
                    unsigned u = *(const unsigned*)(vkh + idx * 32);
                    float f0 = __uint_as_float((u & 0xFFFFu) << 16);
                    float f1 = __uint_as_float(u & 0xFFFF0000u);
                    acc0 += w * f0;
                    acc1 += w * f1;
                }
            }
        }
        __syncthreads();
    }

    s_red[tid][0] = acc0;
    s_red[tid][1] = acc1;
    __syncthreads();
    if (tid < 128) {
        float scale = 1.f / (float)(nvis > 0 ? nvis : 1);
        float a0 = (s_red[tid][0] + s_red[tid + 128][0]) * scale;
        float a1 = (s_red[tid][1] + s_red[tid + 128][1]) * scale;
        int hh = tid >> 4, cc = tid & 15;
        out_sum[(size_t)n * 256 + hh * 32 + cc * 2]     = a0;
        out_sum[(size_t)n * 256 + hh * 32 + cc * 2 + 1] = a1;
    }
    if (tid == 0) visb[n] = (nvis > 0) ? 1.f : 0.f;
}

// ---------------------------------------------------------------------------
__device__ inline float block_sum_256(float v, float* red)
{
    #pragma unroll
    for (int o = 32; o > 0; o >>= 1) v += __shfl_down(v, o, 64);
    int lane = threadIdx.x & 63, w = threadIdx.x >> 6;
    if (lane == 0) red[w] = v;
    __syncthreads();
    float t = red[0] + red[1] + red[2] + red[3];
    __syncthreads();
    return t;
}

// LN1: x = LN( gemm_out + query*(1+vis) + vis*b_out )
__global__ __launch_bounds__(256) void ln1_kernel(
    const float* __restrict__ gin, const float* __restrict__ query,
    const float* __restrict__ visb, const float* __restrict__ b_out,
    const float* __restrict__ g, const float* __restrict__ b,
    float* __restrict__ xout)
{
    __shared__ float red[4];
    int n = blockIdx.x, j = threadIdx.x;
    float vs = visb[n];
    size_t idx = (size_t)n * 256 + j;
    float t = gin[idx] + query[idx] * (1.f + vs) + vs * b_out[j];
    float mu = block_sum_256(t, red) * (1.f / 256.f);
    float d = t - mu;
    float var = block_sum_256(d * d, red) * (1.f / 256.f);
    xout[idx] = d * rsqrtf(var + 1e-5f) * g[j] + b[j];
}

// LN2: out = LN( x + ffn )
__global__ __launch_bounds__(256) void ln2_kernel(
    const float* __restrict__ x, const float* __restrict__ ffn,
    const float* __restrict__ g, const float* __restrict__ b,
    float* __restrict__ out)
{
    __shared__ float red[4];
    int n = blockIdx.x, j = threadIdx.x;
    size_t idx = (size_t)n * 256 + j;
    float t = x[idx] + ffn[idx];
    float mu = block_sum_256(t, red) * (1.f / 256.f);
    float d = t - mu;
    float var = block_sum_256(d * d, red) * (1.f / 256.f);
    out[idx] = d * rsqrtf(var + 1e-5f) * g[j] + b[j];
}

// ---------------------------------------------------------------------------
extern "C" void kernel_launch(void* const* d_in, const int* in_sizes, int n_in,
                              void* d_out, int out_size, void* d_ws, size_t ws_size,
                              hipStream_t stream)
{
    const float* query   = (const float*)d_in[0];
    const float* value   = (const float*)d_in[2];
    const float* refpts  = (const float*)d_in[3];
    const int*   bevmask = (const int*)d_in[6];
    const float* W_value = (const float*)d_in[7];
    const float* b_value = (const float*)d_in[8];
    const float* W_off   = (const float*)d_in[9];
    const float* b_off   = (const float*)d_in[10];
    const float* W_attn  = (const float*)d_in[11];
    const float* b_attn  = (const float*)d_in[12];
    const float* W_out   = (const float*)d_in[13];
    const float* b_out   = (const float*)d_in[14];
    const float* ln1_g   = (const float*)d_in[15];
    const float* ln1_b   = (const float*)d_in[16];
    const float* W1      = (const float*)d_in[17];
    const float* b1      = (const float*)d_in[18];
    const float* W2      = (const float*)d_in[19];
    const float* b2      = (const float*)d_in[20];
    const float* ln2_g   = (const float*)d_in[21];
    const float* ln2_b   = (const float*)d_in[22];
    float* out = (float*)d_out;

    // workspace layout (bytes), temporal aliasing as before
    char* ws = (char*)d_ws;
    unsigned short* vb = (unsigned short*)(ws + 0);
    float* h_ffn  = (float*)(ws + 0);
    float* ln_in  = (float*)(ws + 26214400);
    float* qoff   = (float*)(ws + 49152000);
    float* ffnout = (float*)(ws + 49152000);
    float* qaw    = (float*)(ws + 55705600);
    float* outsum = (float*)(ws + 58982400);
    float* xbuf   = (float*)(ws + 58982400);
    float* visb   = (float*)(ws + 65536000);

    const int MV = NCAMS * LTOT;  // 47874

    // K1: v = value @ W_value + b_value  -> bf16 head-major layout
    mfma_gemm<<<dim3(2, (MV + 127) / 128), 256, 0, stream>>>(
        value, W_value, b_value, nullptr, vb, MV, 256, 256, 2);
    // K2a: qoff = query @ W_off + b_off
    mfma_gemm<<<dim3(2, 50), 256, 0, stream>>>(
        query, W_off, b_off, qoff, nullptr, NQ, 256, 256, 0);
    // K2b: logits = query @ W_attn + b_attn
    mfma_gemm<<<dim3(1, 50), 256, 0, stream>>>(
        query, W_attn, b_attn, qaw, nullptr, NQ, 128, 256, 0);
    // K2c: softmax over 16 per (query, head)
    softmax16_kernel<<<dim3((NQ * 8 + 255) / 256), 256, 0, stream>>>(qaw, NQ * 8);
    // K3: deformable sampling + camera sum + 1/count scaling
    sample_kernel<<<dim3(NQ), 256, 0, stream>>>(
        vb, qoff, qaw, refpts, bevmask, outsum, visb);
    // K4: ln_in = outsum @ W_out (no bias)
    mfma_gemm<<<dim3(2, 50), 256, 0, stream>>>(
        outsum, W_out, nullptr, ln_in, nullptr, NQ, 256, 256, 0);
    // LN1 (fused residual algebra)
    ln1_kernel<<<dim3(NQ), 256, 0, stream>>>(
        ln_in, query, visb, b_out, ln1_g, ln1_b, xbuf);
    // K5: h = relu(x @ W1 + b1)
    mfma_gemm<<<dim3(8, 50), 256, 0, stream>>>(
        xbuf, W1, b1, h_ffn, nullptr, NQ, DFFN, 256, 1);
    // K6: ffnout = h @ W2 + b2
    mfma_gemm<<<dim3(2, 50), 256, 0, stream>>>(
        h_ffn, W2, b2, ffnout, nullptr, NQ, 256, DFFN, 0);
    // LN2 -> output
    ln2_kernel<<<dim3(NQ), 256, 0, stream>>>(
        xbuf, ffnout, ln2_g, ln2_b, out);
}

// Round 4
// 449.067 us; speedup vs baseline: 2.3469x; 1.4861x over previous
//
#include <hip/hip_runtime.h>
#include <math.h>

#define NQ      6400
#define NCAMS   6
#define LTOT    7979
#define DM      256
#define DFFN    1024

typedef __attribute__((ext_vector_type(8))) short bf16x8;
typedef __attribute__((ext_vector_type(4))) float f32x4;

__device__ inline unsigned short f32_to_bf16(float f) {
    unsigned u = __float_as_uint(f);
    unsigned r = u + 0x7FFF + ((u >> 16) & 1);   // round-to-nearest-even
    return (unsigned short)(r >> 16);
}

// ---------------------------------------------------------------------------
// MFMA bf16 GEMM, BM=128 BN=128 BK=32. Used for the value projection (mode 2:
// bf16 head-major (cam, head, pixel, 32ch) output).
// ---------------------------------------------------------------------------
__global__ __launch_bounds__(256) void mfma_gemm128(
    const float* __restrict__ A, const float* __restrict__ B,
    const float* __restrict__ bias, unsigned short* __restrict__ Cb,
    int M, int N, int K)
{
    __shared__ __align__(16) unsigned short As[128][40];
    __shared__ __align__(16) unsigned short Bs[128][40];

    const int tid  = threadIdx.x;
    const int wave = tid >> 6, lane = tid & 63;
    const int wm = wave >> 1, wn = wave & 1;
    const int quad = lane >> 4, l16 = lane & 15;
    const int m0 = blockIdx.y * 128, n0 = blockIdx.x * 128;

    f32x4 acc[4][4] = {};

    for (int k0 = 0; k0 < K; k0 += 32) {
        #pragma unroll
        for (int i = 0; i < 4; ++i) {
            int idx = tid + 256 * i;
            int r = idx >> 3, kc = (idx & 7) * 4;
            int gr = m0 + r;
            float4 f = (gr < M) ? *(const float4*)(A + (size_t)gr * K + k0 + kc)
                                : make_float4(0.f, 0.f, 0.f, 0.f);
            unsigned short* dst = &As[r][kc];
            dst[0] = f32_to_bf16(f.x); dst[1] = f32_to_bf16(f.y);
            dst[2] = f32_to_bf16(f.z); dst[3] = f32_to_bf16(f.w);
        }
        #pragma unroll
        for (int i = 0; i < 4; ++i) {
            int idx = tid + 256 * i;
            int kr = idx >> 5, c = (idx & 31) * 4;
            float4 f = *(const float4*)(B + (size_t)(k0 + kr) * N + n0 + c);
            Bs[c    ][kr] = f32_to_bf16(f.x);
            Bs[c + 1][kr] = f32_to_bf16(f.y);
            Bs[c + 2][kr] = f32_to_bf16(f.z);
            Bs[c + 3][kr] = f32_to_bf16(f.w);
        }
        __syncthreads();
        bf16x8 af[4], bfr[4];
        #pragma unroll
        for (int mi = 0; mi < 4; ++mi)
            af[mi] = *(const bf16x8*)&As[wm * 64 + mi * 16 + l16][quad * 8];
        #pragma unroll
        for (int ni = 0; ni < 4; ++ni)
            bfr[ni] = *(const bf16x8*)&Bs[wn * 64 + ni * 16 + l16][quad * 8];
        #pragma unroll
        for (int mi = 0; mi < 4; ++mi)
            #pragma unroll
            for (int ni = 0; ni < 4; ++ni)
                acc[mi][ni] = __builtin_amdgcn_mfma_f32_16x16x32_bf16(
                    af[mi], bfr[ni], acc[mi][ni], 0, 0, 0);
        __syncthreads();
    }

    #pragma unroll
    for (int mi = 0; mi < 4; ++mi) {
        #pragma unroll
        for (int r = 0; r < 4; ++r) {
            int gm = m0 + wm * 64 + mi * 16 + quad * 4 + r;
            if (gm >= M) continue;
            int cam = gm / LTOT;
            int pix = gm - cam * LTOT;
            #pragma unroll
            for (int ni = 0; ni < 4; ++ni) {
                int gn = n0 + wn * 64 + ni * 16 + l16;
                int head = gn >> 5, ch = gn & 31;
                float v = acc[mi][ni][r] + bias[gn];
                Cb[(((size_t)(cam * 8 + head)) * LTOT + pix) * 32 + ch] = f32_to_bf16(v);
            }
        }
    }
}

// ---------------------------------------------------------------------------
// MFMA bf16 GEMM, BM=64 BN=128 BK=32 (better occupancy for M=6400 GEMMs).
// relu=1 applies ReLU. fp32 out + optional bias.
// ---------------------------------------------------------------------------
__global__ __launch_bounds__(256) void mfma_gemm64(
    const float* __restrict__ A, const float* __restrict__ B,
    const float* __restrict__ bias, float* __restrict__ C,
    int M, int N, int K, int relu)
{
    __shared__ __align__(16) unsigned short As[64][40];
    __shared__ __align__(16) unsigned short Bs[128][40];

    const int tid  = threadIdx.x;
    const int wave = tid >> 6, lane = tid & 63;
    const int wm = wave >> 1, wn = wave & 1;
    const int quad = lane >> 4, l16 = lane & 15;
    const int m0 = blockIdx.y * 64, n0 = blockIdx.x * 128;

    f32x4 acc[2][4] = {};

    for (int k0 = 0; k0 < K; k0 += 32) {
        #pragma unroll
        for (int i = 0; i < 2; ++i) {
            int idx = tid + 256 * i;
            int r = idx >> 3, kc = (idx & 7) * 4;
            int gr = m0 + r;
            float4 f = (gr < M) ? *(const float4*)(A + (size_t)gr * K + k0 + kc)
                                : make_float4(0.f, 0.f, 0.f, 0.f);
            unsigned short* dst = &As[r][kc];
            dst[0] = f32_to_bf16(f.x); dst[1] = f32_to_bf16(f.y);
            dst[2] = f32_to_bf16(f.z); dst[3] = f32_to_bf16(f.w);
        }
        #pragma unroll
        for (int i = 0; i < 4; ++i) {
            int idx = tid + 256 * i;
            int kr = idx >> 5, c = (idx & 31) * 4;
            float4 f = *(const float4*)(B + (size_t)(k0 + kr) * N + n0 + c);
            Bs[c    ][kr] = f32_to_bf16(f.x);
            Bs[c + 1][kr] = f32_to_bf16(f.y);
            Bs[c + 2][kr] = f32_to_bf16(f.z);
            Bs[c + 3][kr] = f32_to_bf16(f.w);
        }
        __syncthreads();
        bf16x8 af[2], bfr[4];
        #pragma unroll
        for (int mi = 0; mi < 2; ++mi)
            af[mi] = *(const bf16x8*)&As[wm * 32 + mi * 16 + l16][quad * 8];
        #pragma unroll
        for (int ni = 0; ni < 4; ++ni)
            bfr[ni] = *(const bf16x8*)&Bs[wn * 64 + ni * 16 + l16][quad * 8];
        #pragma unroll
        for (int mi = 0; mi < 2; ++mi)
            #pragma unroll
            for (int ni = 0; ni < 4; ++ni)
                acc[mi][ni] = __builtin_amdgcn_mfma_f32_16x16x32_bf16(
                    af[mi], bfr[ni], acc[mi][ni], 0, 0, 0);
        __syncthreads();
    }

    #pragma unroll
    for (int mi = 0; mi < 2; ++mi) {
        #pragma unroll
        for (int r = 0; r < 4; ++r) {
            int gm = m0 + wm * 32 + mi * 16 + quad * 4 + r;
            if (gm >= M) continue;
            #pragma unroll
            for (int ni = 0; ni < 4; ++ni) {
                int gn = n0 + wn * 64 + ni * 16 + l16;
                float v = acc[mi][ni][r] + (bias ? bias[gn] : 0.f);
                if (relu) v = fmaxf(v, 0.f);
                C[(size_t)gm * N + gn] = v;
            }
        }
    }
}

// ---------------------------------------------------------------------------
// Fused query projections: blocks x=0,1 compute qoff = query@W_off + b_off
// (cols 0..255); block x=2 computes softmax(query@W_attn + b_attn) -> qaw.
// BM=64. Softmax group of 16 = the 16 lanes (l16) of one MFMA quad.
// ---------------------------------------------------------------------------
__global__ __launch_bounds__(256) void qproj_kernel(
    const float* __restrict__ A,
    const float* __restrict__ W_off, const float* __restrict__ b_off,
    const float* __restrict__ W_attn, const float* __restrict__ b_attn,
    float* __restrict__ qoff, float* __restrict__ qaw)
{
    __shared__ __align__(16) unsigned short As[64][40];
    __shared__ __align__(16) unsigned short Bs[128][40];

    const int tid  = threadIdx.x;
    const int wave = tid >> 6, lane = tid & 63;
    const int wm = wave >> 1, wn = wave & 1;
    const int quad = lane >> 4, l16 = lane & 15;
    const int m0 = blockIdx.y * 64, n0 = blockIdx.x * 128;
    const int is_attn = (n0 == 256);
    const float* Bp  = is_attn ? W_attn : W_off;
    const int Nstride = is_attn ? 128 : 256;
    const int nbase   = is_attn ? 0 : n0;

    f32x4 acc[2][4] = {};

    for (int k0 = 0; k0 < DM; k0 += 32) {
        #pragma unroll
        for (int i = 0; i < 2; ++i) {
            int idx = tid + 256 * i;
            int r = idx >> 3, kc = (idx & 7) * 4;
            float4 f = *(const float4*)(A + (size_t)(m0 + r) * DM + k0 + kc);
            unsigned short* dst = &As[r][kc];
            dst[0] = f32_to_bf16(f.x); dst[1] = f32_to_bf16(f.y);
            dst[2] = f32_to_bf16(f.z); dst[3] = f32_to_bf16(f.w);
        }
        #pragma unroll
        for (int i = 0; i < 4; ++i) {
            int idx = tid + 256 * i;
            int kr = idx >> 5, c = (idx & 31) * 4;
            float4 f = *(const float4*)(Bp + (size_t)(k0 + kr) * Nstride + nbase + c);
            Bs[c    ][kr] = f32_to_bf16(f.x);
            Bs[c + 1][kr] = f32_to_bf16(f.y);
            Bs[c + 2][kr] = f32_to_bf16(f.z);
            Bs[c + 3][kr] = f32_to_bf16(f.w);
        }
        __syncthreads();
        bf16x8 af[2], bfr[4];
        #pragma unroll
        for (int mi = 0; mi < 2; ++mi)
            af[mi] = *(const bf16x8*)&As[wm * 32 + mi * 16 + l16][quad * 8];
        #pragma unroll
        for (int ni = 0; ni < 4; ++ni)
            bfr[ni] = *(const bf16x8*)&Bs[wn * 64 + ni * 16 + l16][quad * 8];
        #pragma unroll
        for (int mi = 0; mi < 2; ++mi)
            #pragma unroll
            for (int ni = 0; ni < 4; ++ni)
                acc[mi][ni] = __builtin_amdgcn_mfma_f32_16x16x32_bf16(
                    af[mi], bfr[ni], acc[mi][ni], 0, 0, 0);
        __syncthreads();
    }

    if (is_attn) {
        #pragma unroll
        for (int mi = 0; mi < 2; ++mi) {
            #pragma unroll
            for (int r = 0; r < 4; ++r) {
                int gm = m0 + wm * 32 + mi * 16 + quad * 4 + r;
                #pragma unroll
                for (int ni = 0; ni < 4; ++ni) {
                    int gn = wn * 64 + ni * 16 + l16;       // 0..127
                    float v = acc[mi][ni][r] + b_attn[gn];
                    float mx = v;
                    #pragma unroll
                    for (int s = 1; s < 16; s <<= 1)
                        mx = fmaxf(mx, __shfl_xor(mx, s, 64));
                    float e = __expf(v - mx);
                    float sum = e;
                    #pragma unroll
                    for (int s = 1; s < 16; s <<= 1)
                        sum += __shfl_xor(sum, s, 64);
                    qaw[(size_t)gm * 128 + gn] = e / sum;
                }
            }
        }
    } else {
        #pragma unroll
        for (int mi = 0; mi < 2; ++mi) {
            #pragma unroll
            for (int r = 0; r < 4; ++r) {
                int gm = m0 + wm * 32 + mi * 16 + quad * 4 + r;
                #pragma unroll
                for (int ni = 0; ni < 4; ++ni) {
                    int gn = n0 + wn * 64 + ni * 16 + l16;
                    qoff[(size_t)gm * 256 + gn] = acc[mi][ni][r] + b_off[gn];
                }
            }
        }
    }
}

// ---------------------------------------------------------------------------
// Head-partitioned deformable sampling. Block = (head = bid&7, 16 queries).
// head -> XCD via round-robin dispatch, so each XCD's L2 holds one head's
// v-slice (6 cams x 7979 x 64B = 3.06 MB < 4 MB L2).
// Setup threads: sq=tid>>4, tuple=(lvl,pt)=tid&15 -- one corner table each.
// Gather threads: gq=tid>>4, c2=tid&15 (2 channels), 64 unconditional loads
// per cam (invalid corners: idx=0, w=0).
// ---------------------------------------------------------------------------
__global__ __launch_bounds__(256) void sample_kernel(
    const unsigned short* __restrict__ vb, // (6, 8, 7979, 32) bf16
    const float* __restrict__ qoff,        // (6400, 256)
    const float* __restrict__ aw,          // (6400, 128) softmaxed
    const float* __restrict__ refpts,      // (6, 1, 6400, 4, 2)
    const int*   __restrict__ bev_mask,    // (6, 1, 6400, 4)
    float* __restrict__ out_sum,           // (6400, 256)
    float* __restrict__ visb)              // (6400)
{
    const int bid = blockIdx.x;
    const int h   = bid & 7;
    const int q0  = (bid >> 3) * 16;
    const int tid = threadIdx.x;
    const int sq  = tid >> 4;          // query slot 0..15
    const int lvl = (tid >> 2) & 3;
    const int n_s = q0 + sq;
    const int c2  = tid & 15;          // channel pair for gather

    __shared__ int   s_idx[4][256];
    __shared__ float s_w[4][256];
    __shared__ float s_vis[NCAMS][16];
    __shared__ int   s_cnt[NCAMS];
    __shared__ int   s_nvis[16];

    if (tid < 96) {
        int cam = tid >> 4, q = tid & 15;
        const int* bm = bev_mask + ((size_t)cam * NQ + q0 + q) * 4;
        s_vis[cam][q] = ((bm[0] + bm[1] + bm[2] + bm[3]) > 0) ? 1.f : 0.f;
    }
    __syncthreads();
    if (tid < NCAMS) {
        float s = 0.f;
        #pragma unroll
        for (int q = 0; q < 16; ++q) s += s_vis[tid][q];
        s_cnt[tid] = (int)s;
    }
    if (tid >= 32 && tid < 48) {
        int q = tid - 32;
        float s = 0.f;
        #pragma unroll
        for (int cam = 0; cam < NCAMS; ++cam) s += s_vis[cam][q];
        s_nvis[q] = (int)s;
    }
    __syncthreads();

    // camera-independent per-tuple data (tuple = tid&15 = lvl*4+pt)
    const float my_aw = aw[(size_t)n_s * 128 + h * 16 + (tid & 15)];
    const float offx  = qoff[(size_t)n_s * 256 + h * 32 + (tid & 15) * 2];
    const float offy  = qoff[(size_t)n_s * 256 + h * 32 + (tid & 15) * 2 + 1];
    const int Wl   = (lvl == 0) ? 100 : (lvl == 1) ? 50 : (lvl == 2) ? 25 : 13;
    const int Hl   = (lvl == 0) ? 60  : (lvl == 1) ? 30 : (lvl == 2) ? 15 : 8;
    const int base = (lvl == 0) ? 0   : (lvl == 1) ? 6000 : (lvl == 2) ? 7500 : 7875;
    const float dx = offx / (float)Wl;
    const float dy = offy / (float)Hl;

    float acc0 = 0.f, acc1 = 0.f;
    for (int k = 0; k < NCAMS; ++k) {
        if (s_cnt[k] == 0) continue;
        {
            const size_t rbase = (((size_t)k * NQ + n_s) * 4 + lvl) * 2;
            float fx = (refpts[rbase + 0] + dx) * (float)Wl - 0.5f;
            float fy = (refpts[rbase + 1] + dy) * (float)Hl - 0.5f;
            float x0f = floorf(fx), y0f = floorf(fy);
            float lx = fx - x0f, ly = fy - y0f;
            int x0 = (int)x0f, y0 = (int)y0f;
            int x1 = x0 + 1, y1 = y0 + 1;
            float wb = my_aw * s_vis[k][sq];
            float w00 = (1.f - lx) * (1.f - ly) * wb;
            float w01 = lx * (1.f - ly) * wb;
            float w10 = (1.f - lx) * ly * wb;
            float w11 = lx * ly * wb;
            bool vx0 = (x0 >= 0) & (x0 < Wl), vx1 = (x1 >= 0) & (x1 < Wl);
            bool vy0 = (y0 >= 0) & (y0 < Hl), vy1 = (y1 >= 0) & (y1 < Hl);
            s_idx[0][tid] = (vx0 & vy0) ? (base + y0 * Wl + x0) : 0;
            s_w[0][tid]   = (vx0 & vy0) ? w00 : 0.f;
            s_idx[1][tid] = (vx1 & vy0) ? (base + y0 * Wl + x1) : 0;
            s_w[1][tid]   = (vx1 & vy0) ? w01 : 0.f;
            s_idx[2][tid] = (vx0 & vy1) ? (base + y1 * Wl + x0) : 0;
            s_w[2][tid]   = (vx0 & vy1) ? w10 : 0.f;
            s_idx[3][tid] = (vx1 & vy1) ? (base + y1 * Wl + x1) : 0;
            s_w[3][tid]   = (vx1 & vy1) ? w11 : 0.f;
        }
        __syncthreads();
        const unsigned short* vkh = vb + (size_t)(k * 8 + h) * LTOT * 32 + c2 * 2;
        #pragma unroll
        for (int t = 0; t < 16; ++t) {
            int tup = (tid & 0xF0) + t;
            #pragma unroll
            for (int corner = 0; corner < 4; ++corner) {
                int idx = s_idx[corner][tup];
                float w = s_w[corner][tup];
                unsigned u = *(const unsigned*)(vkh + (size_t)idx * 32);
                acc0 += w * __uint_as_float(u << 16);
                acc1 += w * __uint_as_float(u & 0xFFFF0000u);
            }
        }
        __syncthreads();
    }

    int nv = s_nvis[sq];
    float scale = 1.f / (float)(nv > 0 ? nv : 1);
    size_t o = (size_t)n_s * 256 + h * 32 + c2 * 2;
    out_sum[o]     = acc0 * scale;
    out_sum[o + 1] = acc1 * scale;
    if (h == 0 && tid < 16) visb[q0 + tid] = (s_nvis[tid] > 0) ? 1.f : 0.f;
}

// ---------------------------------------------------------------------------
__device__ inline float block_sum_256(float v, float* red)
{
    #pragma unroll
    for (int o = 32; o > 0; o >>= 1) v += __shfl_down(v, o, 64);
    int lane = threadIdx.x & 63, w = threadIdx.x >> 6;
    if (lane == 0) red[w] = v;
    __syncthreads();
    float t = red[0] + red[1] + red[2] + red[3];
    __syncthreads();
    return t;
}

// LN1: x = LN( gemm_out + query*(1+vis) + vis*b_out )
__global__ __launch_bounds__(256) void ln1_kernel(
    const float* __restrict__ gin, const float* __restrict__ query,
    const float* __restrict__ visb, const float* __restrict__ b_out,
    const float* __restrict__ g, const float* __restrict__ b,
    float* __restrict__ xout)
{
    __shared__ float red[4];
    int n = blockIdx.x, j = threadIdx.x;
    float vs = visb[n];
    size_t idx = (size_t)n * 256 + j;
    float t = gin[idx] + query[idx] * (1.f + vs) + vs * b_out[j];
    float mu = block_sum_256(t, red) * (1.f / 256.f);
    float d = t - mu;
    float var = block_sum_256(d * d, red) * (1.f / 256.f);
    xout[idx] = d * rsqrtf(var + 1e-5f) * g[j] + b[j];
}

// LN2: out = LN( x + ffn )
__global__ __launch_bounds__(256) void ln2_kernel(
    const float* __restrict__ x, const float* __restrict__ ffn,
    const float* __restrict__ g, const float* __restrict__ b,
    float* __restrict__ out)
{
    __shared__ float red[4];
    int n = blockIdx.x, j = threadIdx.x;
    size_t idx = (size_t)n * 256 + j;
    float t = x[idx] + ffn[idx];
    float mu = block_sum_256(t, red) * (1.f / 256.f);
    float d = t - mu;
    float var = block_sum_256(d * d, red) * (1.f / 256.f);
    out[idx] = d * rsqrtf(var + 1e-5f) * g[j] + b[j];
}

// ---------------------------------------------------------------------------
extern "C" void kernel_launch(void* const* d_in, const int* in_sizes, int n_in,
                              void* d_out, int out_size, void* d_ws, size_t ws_size,
                              hipStream_t stream)
{
    const float* query   = (const float*)d_in[0];
    const float* value   = (const float*)d_in[2];
    const float* refpts  = (const float*)d_in[3];
    const int*   bevmask = (const int*)d_in[6];
    const float* W_value = (const float*)d_in[7];
    const float* b_value = (const float*)d_in[8];
    const float* W_off   = (const float*)d_in[9];
    const float* b_off   = (const float*)d_in[10];
    const float* W_attn  = (const float*)d_in[11];
    const float* b_attn  = (const float*)d_in[12];
    const float* W_out   = (const float*)d_in[13];
    const float* b_out   = (const float*)d_in[14];
    const float* ln1_g   = (const float*)d_in[15];
    const float* ln1_b   = (const float*)d_in[16];
    const float* W1      = (const float*)d_in[17];
    const float* b1      = (const float*)d_in[18];
    const float* W2      = (const float*)d_in[19];
    const float* b2      = (const float*)d_in[20];
    const float* ln2_g   = (const float*)d_in[21];
    const float* ln2_b   = (const float*)d_in[22];
    float* out = (float*)d_out;

    // workspace layout (bytes), temporal aliasing:
    //   [0 ..)          v_bf16 (K1..sample) -> h_ffn (K5..K6)
    //   [26,214,400 ..) ln_in (K4..LN1)
    //   [49,152,000 ..) qoff (K2..sample) -> ffnout (K6..LN2)
    //   [55,705,600 ..) qaw (K2..sample)
    //   [58,982,400 ..) out_sum (sample..K4) -> x (LN1..LN2)
    //   [65,536,000 ..) vis flags
    char* ws = (char*)d_ws;
    unsigned short* vb = (unsigned short*)(ws + 0);
    float* h_ffn  = (float*)(ws + 0);
    float* ln_in  = (float*)(ws + 26214400);
    float* qoff   = (float*)(ws + 49152000);
    float* ffnout = (float*)(ws + 49152000);
    float* qaw    = (float*)(ws + 55705600);
    float* outsum = (float*)(ws + 58982400);
    float* xbuf   = (float*)(ws + 58982400);
    float* visb   = (float*)(ws + 65536000);

    const int MV = NCAMS * LTOT;  // 47874

    // K1: v = value @ W_value + b_value -> bf16 head-major layout
    mfma_gemm128<<<dim3(2, (MV + 127) / 128), 256, 0, stream>>>(
        value, W_value, b_value, vb, MV, 256, 256);
    // K2: fused qoff + attn-softmax projections
    qproj_kernel<<<dim3(3, 100), 256, 0, stream>>>(
        query, W_off, b_off, W_attn, b_attn, qoff, qaw);
    // K3: head-partitioned deformable sampling
    sample_kernel<<<dim3(3200), 256, 0, stream>>>(
        vb, qoff, qaw, refpts, bevmask, outsum, visb);
    // K4: ln_in = outsum @ W_out (no bias)
    mfma_gemm64<<<dim3(2, 100), 256, 0, stream>>>(
        outsum, W_out, nullptr, ln_in, NQ, 256, 256, 0);
    // LN1 (fused residual algebra)
    ln1_kernel<<<dim3(NQ), 256, 0, stream>>>(
        ln_in, query, visb, b_out, ln1_g, ln1_b, xbuf);
    // K5: h = relu(x @ W1 + b1)
    mfma_gemm64<<<dim3(8, 100), 256, 0, stream>>>(
        xbuf, W1, b1, h_ffn, NQ, DFFN, 256, 1);
    // K6: ffnout = h @ W2 + b2
    mfma_gemm64<<<dim3(2, 100), 256, 0, stream>>>(
        h_ffn, W2, b2, ffnout, NQ, 256, DFFN, 0);
    // LN2 -> output
    ln2_kernel<<<dim3(NQ), 256, 0, stream>>>(
        xbuf, ffnout, ln2_g, ln2_b, out);
}

// Round 5
// 332.174 us; speedup vs baseline: 3.1728x; 1.3519x over previous
//
#include <hip/hip_runtime.h>
#include <math.h>

#define NQ      6400
#define NCAMS   6
#define LTOT    7979
#define DM      256
#define DFFN    1024

typedef __attribute__((ext_vector_type(8))) short bf16x8;
typedef __attribute__((ext_vector_type(4))) float f32x4;

__device__ inline unsigned short f32_to_bf16(float f) {
    unsigned u = __float_as_uint(f);
    unsigned r = u + 0x7FFF + ((u >> 16) & 1);   // round-to-nearest-even
    return (unsigned short)(r >> 16);
}

// ---------------------------------------------------------------------------
// Flat fp32 -> bf16 convert, 8 elems/thread.
// ---------------------------------------------------------------------------
__global__ __launch_bounds__(256) void cvt_kernel(
    const float* __restrict__ src, unsigned short* __restrict__ dst, int n8)
{
    int i = blockIdx.x * 256 + threadIdx.x;
    if (i >= n8) return;
    const float4* s = (const float4*)src + (size_t)i * 2;
    float4 a = s[0], b = s[1];
    uint4 o;
    o.x = f32_to_bf16(a.x) | ((unsigned)f32_to_bf16(a.y) << 16);
    o.y = f32_to_bf16(a.z) | ((unsigned)f32_to_bf16(a.w) << 16);
    o.z = f32_to_bf16(b.x) | ((unsigned)f32_to_bf16(b.y) << 16);
    o.w = f32_to_bf16(b.z) | ((unsigned)f32_to_bf16(b.w) << 16);
    *(uint4*)(dst + (size_t)i * 8) = o;
}

// ---------------------------------------------------------------------------
// Weight transpose + convert: WT[n][k] (bf16) = W[k][n] (fp32), all 6 weights
// in one launch via a hardcoded segment table. 32x32 LDS tiles.
// wsT layout (shorts): WvT@0 (64K), WqT@65536 ([384][256]: W_off^T rows 0..255,
// W_attn^T rows 256..383), WoT@163840, W1T@229376 ([1024][256]), W2T@491520
// ([256][1024]).
// ---------------------------------------------------------------------------
__global__ __launch_bounds__(256) void wt_kernel(
    const float* __restrict__ Wv, const float* __restrict__ Woff,
    const float* __restrict__ Wattn, const float* __restrict__ Wout,
    const float* __restrict__ W1, const float* __restrict__ W2,
    unsigned short* __restrict__ wsT)
{
    int b = blockIdx.x;
    const float* src; int K, N, t0, dstoff;
    if (b < 64)       { src = Wv;    K = 256;  N = 256;  t0 = 0;   dstoff = 0; }
    else if (b < 128) { src = Woff;  K = 256;  N = 256;  t0 = 64;  dstoff = 65536; }
    else if (b < 160) { src = Wattn; K = 256;  N = 128;  t0 = 128; dstoff = 131072; }
    else if (b < 224) { src = Wout;  K = 256;  N = 256;  t0 = 160; dstoff = 163840; }
    else if (b < 480) { src = W1;    K = 256;  N = 1024; t0 = 224; dstoff = 229376; }
    else              { src = W2;    K = 1024; N = 256;  t0 = 480; dstoff = 491520; }
    int t = b - t0;
    int ntn = N >> 5;
    int kt = t / ntn, nt = t - kt * ntn;
    __shared__ float tile[32][33];
    int tx = threadIdx.x & 31, ty = threadIdx.x >> 5;
    #pragma unroll
    for (int i = 0; i < 4; ++i)
        tile[ty + i * 8][tx] = src[(size_t)(kt * 32 + ty + i * 8) * N + nt * 32 + tx];
    __syncthreads();
    #pragma unroll
    for (int i = 0; i < 4; ++i) {
        int nn = nt * 32 + ty + i * 8;
        wsT[dstoff + (size_t)nn * K + kt * 32 + tx] = f32_to_bf16(tile[tx][ty + i * 8]);
    }
}

// ---------------------------------------------------------------------------
// MFMA bf16 GEMM (pre-converted bf16 inputs), BM=128 BN=128 BK=32, used for
// the value projection -> bf16 head-major (cam, head, pixel, 32ch) output.
// A[M][K] bf16, BT[N][K] bf16, bias fp32.
// ---------------------------------------------------------------------------
__global__ __launch_bounds__(256) void gemm_v_kernel(
    const unsigned short* __restrict__ A, const unsigned short* __restrict__ BT,
    const float* __restrict__ bias, unsigned short* __restrict__ Cb, int M)
{
    const int K = 256;
    __shared__ __align__(16) unsigned short As[128][40];
    __shared__ __align__(16) unsigned short Bs[128][40];

    const int tid  = threadIdx.x;
    const int wave = tid >> 6, lane = tid & 63;
    const int wm = wave >> 1, wn = wave & 1;
    const int quad = lane >> 4, l16 = lane & 15;
    const int m0 = blockIdx.y * 128, n0 = blockIdx.x * 128;

    f32x4 acc[4][4] = {};

    for (int k0 = 0; k0 < K; k0 += 32) {
        #pragma unroll
        for (int i = 0; i < 2; ++i) {
            int idx = tid + 256 * i;
            int r = idx >> 2, kc = (idx & 3) * 8;
            int gr = m0 + r;
            uint4 d = (gr < M) ? *(const uint4*)(A + (size_t)gr * K + k0 + kc)
                               : make_uint4(0u, 0u, 0u, 0u);
            uint2* dst = (uint2*)&As[r][kc];
            dst[0] = make_uint2(d.x, d.y);
            dst[1] = make_uint2(d.z, d.w);
        }
        #pragma unroll
        for (int i = 0; i < 2; ++i) {
            int idx = tid + 256 * i;
            int r = idx >> 2, kc = (idx & 3) * 8;
            uint4 d = *(const uint4*)(BT + (size_t)(n0 + r) * K + k0 + kc);
            uint2* dst = (uint2*)&Bs[r][kc];
            dst[0] = make_uint2(d.x, d.y);
            dst[1] = make_uint2(d.z, d.w);
        }
        __syncthreads();
        bf16x8 af[4], bfr[4];
        #pragma unroll
        for (int mi = 0; mi < 4; ++mi)
            af[mi] = *(const bf16x8*)&As[wm * 64 + mi * 16 + l16][quad * 8];
        #pragma unroll
        for (int ni = 0; ni < 4; ++ni)
            bfr[ni] = *(const bf16x8*)&Bs[wn * 64 + ni * 16 + l16][quad * 8];
        #pragma unroll
        for (int mi = 0; mi < 4; ++mi)
            #pragma unroll
            for (int ni = 0; ni < 4; ++ni)
                acc[mi][ni] = __builtin_amdgcn_mfma_f32_16x16x32_bf16(
                    af[mi], bfr[ni], acc[mi][ni], 0, 0, 0);
        __syncthreads();
    }

    #pragma unroll
    for (int mi = 0; mi < 4; ++mi) {
        #pragma unroll
        for (int r = 0; r < 4; ++r) {
            int gm = m0 + wm * 64 + mi * 16 + quad * 4 + r;
            if (gm >= M) continue;
            int cam = gm / LTOT;
            int pix = gm - cam * LTOT;
            #pragma unroll
            for (int ni = 0; ni < 4; ++ni) {
                int gn = n0 + wn * 64 + ni * 16 + l16;
                int head = gn >> 5, ch = gn & 31;
                float v = acc[mi][ni][r] + bias[gn];
                Cb[(((size_t)(cam * 8 + head)) * LTOT + pix) * 32 + ch] = f32_to_bf16(v);
            }
        }
    }
}

// ---------------------------------------------------------------------------
// MFMA bf16 GEMM, BM=64 BN=128 BK=32, bf16 A + BT inputs.
// mode 0: fp32 out (+bias opt); mode 1: relu -> bf16 out.
// ---------------------------------------------------------------------------
__global__ __launch_bounds__(256) void gemm64_kernel(
    const unsigned short* __restrict__ A, const unsigned short* __restrict__ BT,
    const float* __restrict__ bias, float* __restrict__ C,
    unsigned short* __restrict__ Cb,
    int M, int N, int K, int mode)
{
    __shared__ __align__(16) unsigned short As[64][40];
    __shared__ __align__(16) unsigned short Bs[128][40];

    const int tid  = threadIdx.x;
    const int wave = tid >> 6, lane = tid & 63;
    const int wm = wave >> 1, wn = wave & 1;
    const int quad = lane >> 4, l16 = lane & 15;
    const int m0 = blockIdx.y * 64, n0 = blockIdx.x * 128;

    f32x4 acc[2][4] = {};

    for (int k0 = 0; k0 < K; k0 += 32) {
        {
            int r = tid >> 2, kc = (tid & 3) * 8;
            int gr = m0 + r;
            uint4 d = (gr < M) ? *(const uint4*)(A + (size_t)gr * K + k0 + kc)
                               : make_uint4(0u, 0u, 0u, 0u);
            uint2* dst = (uint2*)&As[r][kc];
            dst[0] = make_uint2(d.x, d.y);
            dst[1] = make_uint2(d.z, d.w);
        }
        #pragma unroll
        for (int i = 0; i < 2; ++i) {
            int idx = tid + 256 * i;
            int r = idx >> 2, kc = (idx & 3) * 8;
            uint4 d = *(const uint4*)(BT + (size_t)(n0 + r) * K + k0 + kc);
            uint2* dst = (uint2*)&Bs[r][kc];
            dst[0] = make_uint2(d.x, d.y);
            dst[1] = make_uint2(d.z, d.w);
        }
        __syncthreads();
        bf16x8 af[2], bfr[4];
        #pragma unroll
        for (int mi = 0; mi < 2; ++mi)
            af[mi] = *(const bf16x8*)&As[wm * 32 + mi * 16 + l16][quad * 8];
        #pragma unroll
        for (int ni = 0; ni < 4; ++ni)
            bfr[ni] = *(const bf16x8*)&Bs[wn * 64 + ni * 16 + l16][quad * 8];
        #pragma unroll
        for (int mi = 0; mi < 2; ++mi)
            #pragma unroll
            for (int ni = 0; ni < 4; ++ni)
                acc[mi][ni] = __builtin_amdgcn_mfma_f32_16x16x32_bf16(
                    af[mi], bfr[ni], acc[mi][ni], 0, 0, 0);
        __syncthreads();
    }

    #pragma unroll
    for (int mi = 0; mi < 2; ++mi) {
        #pragma unroll
        for (int r = 0; r < 4; ++r) {
            int gm = m0 + wm * 32 + mi * 16 + quad * 4 + r;
            if (gm >= M) continue;
            #pragma unroll
            for (int ni = 0; ni < 4; ++ni) {
                int gn = n0 + wn * 64 + ni * 16 + l16;
                float v = acc[mi][ni][r] + (bias ? bias[gn] : 0.f);
                if (mode == 1) {
                    Cb[(size_t)gm * N + gn] = f32_to_bf16(fmaxf(v, 0.f));
                } else {
                    C[(size_t)gm * N + gn] = v;
                }
            }
        }
    }
}

// ---------------------------------------------------------------------------
// Fused query projections off the combined WqT [384][256]: blocks x=0,1 ->
// qoff cols 0..255; x=2 -> softmax(attn logits) -> qaw. BM=64.
// ---------------------------------------------------------------------------
__global__ __launch_bounds__(256) void qproj_kernel(
    const unsigned short* __restrict__ A, const unsigned short* __restrict__ WqT,
    const float* __restrict__ b_off, const float* __restrict__ b_attn,
    float* __restrict__ qoff, float* __restrict__ qaw)
{
    const int K = 256;
    __shared__ __align__(16) unsigned short As[64][40];
    __shared__ __align__(16) unsigned short Bs[128][40];

    const int tid  = threadIdx.x;
    const int wave = tid >> 6, lane = tid & 63;
    const int wm = wave >> 1, wn = wave & 1;
    const int quad = lane >> 4, l16 = lane & 15;
    const int m0 = blockIdx.y * 64, n0 = blockIdx.x * 128;
    const int is_attn = (n0 == 256);

    f32x4 acc[2][4] = {};

    for (int k0 = 0; k0 < K; k0 += 32) {
        {
            int r = tid >> 2, kc = (tid & 3) * 8;
            uint4 d = *(const uint4*)(A + (size_t)(m0 + r) * K + k0 + kc);
            uint2* dst = (uint2*)&As[r][kc];
            dst[0] = make_uint2(d.x, d.y);
            dst[1] = make_uint2(d.z, d.w);
        }
        #pragma unroll
        for (int i = 0; i < 2; ++i) {
            int idx = tid + 256 * i;
            int r = idx >> 2, kc = (idx & 3) * 8;
            uint4 d = *(const uint4*)(WqT + (size_t)(n0 + r) * K + k0 + kc);
            uint2* dst = (uint2*)&Bs[r][kc];
            dst[0] = make_uint2(d.x, d.y);
            dst[1] = make_uint2(d.z, d.w);
        }
        __syncthreads();
        bf16x8 af[2], bfr[4];
        #pragma unroll
        for (int mi = 0; mi < 2; ++mi)
            af[mi] = *(const bf16x8*)&As[wm * 32 + mi * 16 + l16][quad * 8];
        #pragma unroll
        for (int ni = 0; ni < 4; ++ni)
            bfr[ni] = *(const bf16x8*)&Bs[wn * 64 + ni * 16 + l16][quad * 8];
        #pragma unroll
        for (int mi = 0; mi < 2; ++mi)
            #pragma unroll
            for (int ni = 0; ni < 4; ++ni)
                acc[mi][ni] = __builtin_amdgcn_mfma_f32_16x16x32_bf16(
                    af[mi], bfr[ni], acc[mi][ni], 0, 0, 0);
        __syncthreads();
    }

    if (is_attn) {
        #pragma unroll
        for (int mi = 0; mi < 2; ++mi) {
            #pragma unroll
            for (int r = 0; r < 4; ++r) {
                int gm = m0 + wm * 32 + mi * 16 + quad * 4 + r;
                #pragma unroll
                for (int ni = 0; ni < 4; ++ni) {
                    int gn = wn * 64 + ni * 16 + l16;
                    float v = acc[mi][ni][r] + b_attn[gn];
                    float mx = v;
                    #pragma unroll
                    for (int s = 1; s < 16; s <<= 1)
                        mx = fmaxf(mx, __shfl_xor(mx, s, 64));
                    float e = __expf(v - mx);
                    float sum = e;
                    #pragma unroll
                    for (int s = 1; s < 16; s <<= 1)
                        sum += __shfl_xor(sum, s, 64);
                    qaw[(size_t)gm * 128 + gn] = e / sum;
                }
            }
        }
    } else {
        #pragma unroll
        for (int mi = 0; mi < 2; ++mi) {
            #pragma unroll
            for (int r = 0; r < 4; ++r) {
                int gm = m0 + wm * 32 + mi * 16 + quad * 4 + r;
                #pragma unroll
                for (int ni = 0; ni < 4; ++ni) {
                    int gn = n0 + wn * 64 + ni * 16 + l16;
                    qoff[(size_t)gm * 256 + gn] = acc[mi][ni][r] + b_off[gn];
                }
            }
        }
    }
}

// ---------------------------------------------------------------------------
// Head-partitioned deformable sampling (wide-gather version).
// Block = (head = bid&7, 16 queries); head -> XCD via round-robin dispatch.
// Setup: tid -> (sq=tid>>4, tuple=tid&15), packs (byte_off, weight) into
//        s_tab with a 17-stride swizzle (bank-conflict-free gather reads).
// Gather: tid -> (sq=tid>>4, tg=(tid>>2)&3, cg=tid&3); uint4 loads of 8 ch,
//        4 tuples x 4 corners each; shuffle-xor reduce over tg; bf16 out.
// ---------------------------------------------------------------------------
__global__ __launch_bounds__(256) void sample_kernel(
    const unsigned short* __restrict__ vb, // (6, 8, 7979, 32) bf16
    const float* __restrict__ qoff,        // (6400, 256)
    const float* __restrict__ aw,          // (6400, 128) softmaxed
    const float* __restrict__ refpts,      // (6, 1, 6400, 4, 2)
    const int*   __restrict__ bev_mask,    // (6, 1, 6400, 4)
    unsigned short* __restrict__ outsum,   // (6400, 256) bf16
    float* __restrict__ visb)              // (6400)
{
    const int bid = blockIdx.x;
    const int h   = bid & 7;
    const int q0  = (bid >> 3) * 16;
    const int tid = threadIdx.x;
    const int sq  = tid >> 4;          // query slot 0..15 (setup & gather)
    const int tup = tid & 15;          // setup tuple
    const int lvl = tup >> 2;
    const int n_s = q0 + sq;
    const int tg  = (tid >> 2) & 3;    // gather tuple group
    const int cg  = tid & 3;           // gather channel group (8 ch)

    __shared__ int2  s_tab[4][272];    // [corner][sq*17 + tup]
    __shared__ float s_vis[NCAMS][16];
    __shared__ int   s_cnt[NCAMS];
    __shared__ int   s_nvis[16];

    if (tid < 96) {
        int cam = tid >> 4, q = tid & 15;
        const int* bm = bev_mask + ((size_t)cam * NQ + q0 + q) * 4;
        s_vis[cam][q] = ((bm[0] + bm[1] + bm[2] + bm[3]) > 0) ? 1.f : 0.f;
    }
    __syncthreads();
    if (tid < NCAMS) {
        float s = 0.f;
        #pragma unroll
        for (int q = 0; q < 16; ++q) s += s_vis[tid][q];
        s_cnt[tid] = (int)s;
    }
    if (tid >= 32 && tid < 48) {
        int q = tid - 32;
        float s = 0.f;
        #pragma unroll
        for (int cam = 0; cam < NCAMS; ++cam) s += s_vis[cam][q];
        s_nvis[q] = (int)s;
    }
    __syncthreads();

    // camera-independent per-tuple data
    const float my_aw = aw[(size_t)n_s * 128 + h * 16 + tup];
    const float offx  = qoff[(size_t)n_s * 256 + h * 32 + tup * 2];
    const float offy  = qoff[(size_t)n_s * 256 + h * 32 + tup * 2 + 1];
    const int Wl   = (lvl == 0) ? 100 : (lvl == 1) ? 50 : (lvl == 2) ? 25 : 13;
    const int Hl   = (lvl == 0) ? 60  : (lvl == 1) ? 30 : (lvl == 2) ? 15 : 8;
    const int base = (lvl == 0) ? 0   : (lvl == 1) ? 6000 : (lvl == 2) ? 7500 : 7875;
    const float dx = offx / (float)Wl;
    const float dy = offy / (float)Hl;
    const int tabi = sq * 17 + tup;

    float a0 = 0.f, a1 = 0.f, a2 = 0.f, a3 = 0.f;
    float a4 = 0.f, a5 = 0.f, a6 = 0.f, a7 = 0.f;

    for (int k = 0; k < NCAMS; ++k) {
        if (s_cnt[k] == 0) continue;
        {
            const size_t rbase = (((size_t)k * NQ + n_s) * 4 + lvl) * 2;
            float fx = (refpts[rbase + 0] + dx) * (float)Wl - 0.5f;
            float fy = (refpts[rbase + 1] + dy) * (float)Hl - 0.5f;
            float x0f = floorf(fx), y0f = floorf(fy);
            float lx = fx - x0f, ly = fy - y0f;
            int x0 = (int)x0f, y0 = (int)y0f;
            int x1 = x0 + 1, y1 = y0 + 1;
            float wb = my_aw * s_vis[k][sq];
            float w00 = (1.f - lx) * (1.f - ly) * wb;
            float w01 = lx * (1.f - ly) * wb;
            float w10 = (1.f - lx) * ly * wb;
            float w11 = lx * ly * wb;
            bool vx0 = (x0 >= 0) & (x0 < Wl), vx1 = (x1 >= 0) & (x1 < Wl);
            bool vy0 = (y0 >= 0) & (y0 < Hl), vy1 = (y1 >= 0) & (y1 < Hl);
            s_tab[0][tabi] = make_int2((vx0 & vy0) ? (base + y0 * Wl + x0) * 64 : 0,
                                       __float_as_int((vx0 & vy0) ? w00 : 0.f));
            s_tab[1][tabi] = make_int2((vx1 & vy0) ? (base + y0 * Wl + x1) * 64 : 0,
                                       __float_as_int((vx1 & vy0) ? w01 : 0.f));
            s_tab[2][tabi] = make_int2((vx0 & vy1) ? (base + y1 * Wl + x0) * 64 : 0,
                                       __float_as_int((vx0 & vy1) ? w10 : 0.f));
            s_tab[3][tabi] = make_int2((vx1 & vy1) ? (base + y1 * Wl + x1) * 64 : 0,
                                       __float_as_int((vx1 & vy1) ? w11 : 0.f));
        }
        __syncthreads();
        const char* vkh = (const char*)vb + (size_t)(k * 8 + h) * (LTOT * 64) + cg * 16;
        #pragma unroll
        for (int j = 0; j < 4; ++j) {
            int ti = sq * 17 + tg * 4 + j;
            #pragma unroll
            for (int corner = 0; corner < 4; ++corner) {
                int2 t = s_tab[corner][ti];
                float w = __int_as_float(t.y);
                uint4 d = *(const uint4*)(vkh + t.x);
                a0 += w * __uint_as_float(d.x << 16);
                a1 += w * __uint_as_float(d.x & 0xFFFF0000u);
                a2 += w * __uint_as_float(d.y << 16);
                a3 += w * __uint_as_float(d.y & 0xFFFF0000u);
                a4 += w * __uint_as_float(d.z << 16);
                a5 += w * __uint_as_float(d.z & 0xFFFF0000u);
                a6 += w * __uint_as_float(d.w << 16);
                a7 += w * __uint_as_float(d.w & 0xFFFF0000u);
            }
        }
        __syncthreads();
    }

    // reduce across tuple groups (tid bits 2,3 -> xor masks 4, 8; same wave)
    a0 += __shfl_xor(a0, 4, 64); a0 += __shfl_xor(a0, 8, 64);
    a1 += __shfl_xor(a1, 4, 64); a1 += __shfl_xor(a1, 8, 64);
    a2 += __shfl_xor(a2, 4, 64); a2 += __shfl_xor(a2, 8, 64);
    a3 += __shfl_xor(a3, 4, 64); a3 += __shfl_xor(a3, 8, 64);
    a4 += __shfl_xor(a4, 4, 64); a4 += __shfl_xor(a4, 8, 64);
    a5 += __shfl_xor(a5, 4, 64); a5 += __shfl_xor(a5, 8, 64);
    a6 += __shfl_xor(a6, 4, 64); a6 += __shfl_xor(a6, 8, 64);
    a7 += __shfl_xor(a7, 4, 64); a7 += __shfl_xor(a7, 8, 64);

    if ((tid & 12) == 0) {
        int nv = s_nvis[sq];
        float sc = 1.f / (float)(nv > 0 ? nv : 1);
        uint4 o;
        o.x = f32_to_bf16(a0 * sc) | ((unsigned)f32_to_bf16(a1 * sc) << 16);
        o.y = f32_to_bf16(a2 * sc) | ((unsigned)f32_to_bf16(a3 * sc) << 16);
        o.z = f32_to_bf16(a4 * sc) | ((unsigned)f32_to_bf16(a5 * sc) << 16);
        o.w = f32_to_bf16(a6 * sc) | ((unsigned)f32_to_bf16(a7 * sc) << 16);
        *(uint4*)(outsum + (size_t)n_s * 256 + h * 32 + cg * 8) = o;
    }
    if (h == 0 && tid < 16) visb[q0 + tid] = (s_nvis[tid] > 0) ? 1.f : 0.f;
}

// ---------------------------------------------------------------------------
__device__ inline float block_sum_256(float v, float* red)
{
    #pragma unroll
    for (int o = 32; o > 0; o >>= 1) v += __shfl_down(v, o, 64);
    int lane = threadIdx.x & 63, w = threadIdx.x >> 6;
    if (lane == 0) red[w] = v;
    __syncthreads();
    float t = red[0] + red[1] + red[2] + red[3];
    __syncthreads();
    return t;
}

// LN1: x = LN( gemm_out + query*(1+vis) + vis*b_out ), fp32 + bf16 outputs
__global__ __launch_bounds__(256) void ln1_kernel(
    const float* __restrict__ gin, const float* __restrict__ query,
    const float* __restrict__ visb, const float* __restrict__ b_out,
    const float* __restrict__ g, const float* __restrict__ b,
    float* __restrict__ xout, unsigned short* __restrict__ xbf)
{
    __shared__ float red[4];
    int n = blockIdx.x, j = threadIdx.x;
    float vs = visb[n];
    size_t idx = (size_t)n * 256 + j;
    float t = gin[idx] + query[idx] * (1.f + vs) + vs * b_out[j];
    float mu = block_sum_256(t, red) * (1.f / 256.f);
    float d = t - mu;
    float var = block_sum_256(d * d, red) * (1.f / 256.f);
    float res = d * rsqrtf(var + 1e-5f) * g[j] + b[j];
    xout[idx] = res;
    xbf[idx] = f32_to_bf16(res);
}

// LN2: out = LN( x + ffn )
__global__ __launch_bounds__(256) void ln2_kernel(
    const float* __restrict__ x, const float* __restrict__ ffn,
    const float* __restrict__ g, const float* __restrict__ b,
    float* __restrict__ out)
{
    __shared__ float red[4];
    int n = blockIdx.x, j = threadIdx.x;
    size_t idx = (size_t)n * 256 + j;
    float t = x[idx] + ffn[idx];
    float mu = block_sum_256(t, red) * (1.f / 256.f);
    float d = t - mu;
    float var = block_sum_256(d * d, red) * (1.f / 256.f);
    out[idx] = d * rsqrtf(var + 1e-5f) * g[j] + b[j];
}

// ---------------------------------------------------------------------------
extern "C" void kernel_launch(void* const* d_in, const int* in_sizes, int n_in,
                              void* d_out, int out_size, void* d_ws, size_t ws_size,
                              hipStream_t stream)
{
    const float* query   = (const float*)d_in[0];
    const float* value   = (const float*)d_in[2];
    const float* refpts  = (const float*)d_in[3];
    const int*   bevmask = (const int*)d_in[6];
    const float* W_value = (const float*)d_in[7];
    const float* b_value = (const float*)d_in[8];
    const float* W_off   = (const float*)d_in[9];
    const float* b_off   = (const float*)d_in[10];
    const float* W_attn  = (const float*)d_in[11];
    const float* b_attn  = (const float*)d_in[12];
    const float* W_out   = (const float*)d_in[13];
    const float* b_out   = (const float*)d_in[14];
    const float* ln1_g   = (const float*)d_in[15];
    const float* ln1_b   = (const float*)d_in[16];
    const float* W1      = (const float*)d_in[17];
    const float* b1      = (const float*)d_in[18];
    const float* W2      = (const float*)d_in[19];
    const float* b2      = (const float*)d_in[20];
    const float* ln2_g   = (const float*)d_in[21];
    const float* ln2_b   = (const float*)d_in[22];
    float* out = (float*)d_out;

    // workspace layout (byte offsets; temporal aliasing documented per region):
    //  [0)           vb bf16 24,511,488   (K1 -> sample)
    //  [0)           xbuf fp32 6,553,600  (LN1 -> LN2)   [vb dead]
    //  [7,000,000)   ln_in fp32 6,553,600 (K4 -> LN1)    [vb dead]
    //  [14,000,000)  xbf bf16 3,276,800   (LN1 -> K5)    [vb dead]
    //  [24,600,000)  value_bf 24,511,488  (cvt -> K1)
    //  [24,600,000)  qoff fp32 6,553,600  (qproj -> sample) [value_bf dead]
    //  [31,200,000)  qaw fp32 3,276,800   (qproj -> sample)
    //  [34,500,000)  outsum_bf 3,276,800  (sample -> K4)
    //  [37,800,000)  hbf bf16 13,107,200  (K5 -> K6)
    //  [51,000,000)  query_bf 3,276,800   (cvt -> qproj)
    //  [54,300,000)  ffnout fp32 6,553,600 (K6 -> LN2)
    //  [60,900,000)  visb 25,600
    //  [61,000,000)  wsT bf16 1,507,328   (wt -> K6)
    char* ws = (char*)d_ws;
    unsigned short* vb       = (unsigned short*)(ws + 0);
    float*          xbuf     = (float*)(ws + 0);
    float*          ln_in    = (float*)(ws + 7000000);
    unsigned short* xbf      = (unsigned short*)(ws + 14000000);
    unsigned short* value_bf = (unsigned short*)(ws + 24600000);
    float*          qoff     = (float*)(ws + 24600000);
    float*          qaw      = (float*)(ws + 31200000);
    unsigned short* outsum   = (unsigned short*)(ws + 34500000);
    unsigned short* hbf      = (unsigned short*)(ws + 37800000);
    unsigned short* query_bf = (unsigned short*)(ws + 51000000);
    float*          ffnout   = (float*)(ws + 54300000);
    float*          visb     = (float*)(ws + 60900000);
    unsigned short* wsT      = (unsigned short*)(ws + 61000000);

    unsigned short* WvT = wsT;            // [256][256]
    unsigned short* WqT = wsT + 65536;    // [384][256]
    unsigned short* WoT = wsT + 163840;   // [256][256]
    unsigned short* W1T = wsT + 229376;   // [1024][256]
    unsigned short* W2T = wsT + 491520;   // [256][1024]

    const int MV = NCAMS * LTOT;  // 47874

    // P1: convert value & query to bf16; transpose+convert all weights
    cvt_kernel<<<dim3((MV * 256 / 8 + 255) / 256), 256, 0, stream>>>(
        value, value_bf, MV * 256 / 8);
    cvt_kernel<<<dim3((NQ * 256 / 8 + 255) / 256), 256, 0, stream>>>(
        query, query_bf, NQ * 256 / 8);
    wt_kernel<<<dim3(736), 256, 0, stream>>>(
        W_value, W_off, W_attn, W_out, W1, W2, wsT);
    // K1: v = value @ W_value + b_value -> bf16 head-major layout
    gemm_v_kernel<<<dim3(2, (MV + 127) / 128), 256, 0, stream>>>(
        value_bf, WvT, b_value, vb, MV);
    // K2: fused qoff + attn-softmax projections
    qproj_kernel<<<dim3(3, 100), 256, 0, stream>>>(
        query_bf, WqT, b_off, b_attn, qoff, qaw);
    // K3: head-partitioned deformable sampling -> bf16 outsum
    sample_kernel<<<dim3(3200), 256, 0, stream>>>(
        vb, qoff, qaw, refpts, bevmask, outsum, visb);
    // K4: ln_in = outsum @ W_out (no bias)
    gemm64_kernel<<<dim3(2, 100), 256, 0, stream>>>(
        outsum, WoT, nullptr, ln_in, nullptr, NQ, 256, 256, 0);
    // LN1 (fused residual algebra), fp32 + bf16 out
    ln1_kernel<<<dim3(NQ), 256, 0, stream>>>(
        ln_in, query, visb, b_out, ln1_g, ln1_b, xbuf, xbf);
    // K5: hbf = bf16(relu(x @ W1 + b1))
    gemm64_kernel<<<dim3(8, 100), 256, 0, stream>>>(
        xbf, W1T, b1, nullptr, hbf, NQ, DFFN, 256, 1);
    // K6: ffnout = h @ W2 + b2
    gemm64_kernel<<<dim3(2, 100), 256, 0, stream>>>(
        hbf, W2T, b2, ffnout, nullptr, NQ, 256, DFFN, 0);
    // LN2 -> output
    ln2_kernel<<<dim3(NQ), 256, 0, stream>>>(
        xbuf, ffnout, ln2_g, ln2_b, out);
}

// Round 6
// 321.719 us; speedup vs baseline: 3.2759x; 1.0325x over previous
//
#include <hip/hip_runtime.h>
#include <math.h>

#define NQ      6400
#define NCAMS   6
#define LTOT    7979
#define DM      256
#define DFFN    1024

typedef __attribute__((ext_vector_type(8))) short bf16x8;
typedef __attribute__((ext_vector_type(4))) float f32x4;

__device__ inline unsigned short f32_to_bf16(float f) {
    unsigned u = __float_as_uint(f);
    unsigned r = u + 0x7FFF + ((u >> 16) & 1);   // round-to-nearest-even
    return (unsigned short)(r >> 16);
}

// ---------------------------------------------------------------------------
// Weight transpose + convert: WT[n][k] (bf16) = W[k][n] (fp32), all weights
// in one launch. wsT layout (shorts): WvT@0, WqT@65536 ([384][256]),
// WoT@163840, W1T@229376 ([1024][256]), W2T@491520 ([256][1024]).
// ---------------------------------------------------------------------------
__global__ __launch_bounds__(256) void wt_kernel(
    const float* __restrict__ Wv, const float* __restrict__ Woff,
    const float* __restrict__ Wattn, const float* __restrict__ Wout,
    const float* __restrict__ W1, const float* __restrict__ W2,
    unsigned short* __restrict__ wsT)
{
    int b = blockIdx.x;
    const float* src; int K, N, t0, dstoff;
    if (b < 64)       { src = Wv;    K = 256;  N = 256;  t0 = 0;   dstoff = 0; }
    else if (b < 128) { src = Woff;  K = 256;  N = 256;  t0 = 64;  dstoff = 65536; }
    else if (b < 160) { src = Wattn; K = 256;  N = 128;  t0 = 128; dstoff = 131072; }
    else if (b < 224) { src = Wout;  K = 256;  N = 256;  t0 = 160; dstoff = 163840; }
    else if (b < 480) { src = W1;    K = 256;  N = 1024; t0 = 224; dstoff = 229376; }
    else              { src = W2;    K = 1024; N = 256;  t0 = 480; dstoff = 491520; }
    int t = b - t0;
    int ntn = N >> 5;
    int kt = t / ntn, nt = t - kt * ntn;
    __shared__ float tile[32][33];
    int tx = threadIdx.x & 31, ty = threadIdx.x >> 5;
    #pragma unroll
    for (int i = 0; i < 4; ++i)
        tile[ty + i * 8][tx] = src[(size_t)(kt * 32 + ty + i * 8) * N + nt * 32 + tx];
    __syncthreads();
    #pragma unroll
    for (int i = 0; i < 4; ++i) {
        int nn = nt * 32 + ty + i * 8;
        wsT[dstoff + (size_t)nn * K + kt * 32 + tx] = f32_to_bf16(tile[tx][ty + i * 8]);
    }
}

// ---------------------------------------------------------------------------
// Value projection: A fp32 (converted inline while staging), BT bf16.
// BM=BN=128, BK=32 -> bf16 head-major (cam, head, pixel, 32ch) output.
// ---------------------------------------------------------------------------
__global__ __launch_bounds__(256) void gemm_v_kernel(
    const float* __restrict__ A, const unsigned short* __restrict__ BT,
    const float* __restrict__ bias, unsigned short* __restrict__ Cb, int M)
{
    const int K = 256;
    __shared__ __align__(16) unsigned short As[128][40];
    __shared__ __align__(16) unsigned short Bs[128][40];

    const int tid  = threadIdx.x;
    const int wave = tid >> 6, lane = tid & 63;
    const int wm = wave >> 1, wn = wave & 1;
    const int quad = lane >> 4, l16 = lane & 15;
    const int m0 = blockIdx.y * 128, n0 = blockIdx.x * 128;

    f32x4 acc[4][4] = {};

    for (int k0 = 0; k0 < K; k0 += 32) {
        #pragma unroll
        for (int i = 0; i < 2; ++i) {            // A: 128x32 fp32 -> bf16
            int idx = tid + 256 * i;
            int r = idx >> 2, kc = (idx & 3) * 8;
            int gr = m0 + r;
            float4 f0, f1;
            if (gr < M) {
                f0 = *(const float4*)(A + (size_t)gr * K + k0 + kc);
                f1 = *(const float4*)(A + (size_t)gr * K + k0 + kc + 4);
            } else { f0 = make_float4(0,0,0,0); f1 = f0; }
            uint4 o;
            o.x = f32_to_bf16(f0.x) | ((unsigned)f32_to_bf16(f0.y) << 16);
            o.y = f32_to_bf16(f0.z) | ((unsigned)f32_to_bf16(f0.w) << 16);
            o.z = f32_to_bf16(f1.x) | ((unsigned)f32_to_bf16(f1.y) << 16);
            o.w = f32_to_bf16(f1.z) | ((unsigned)f32_to_bf16(f1.w) << 16);
            *(uint4*)&As[r][kc] = o;
        }
        #pragma unroll
        for (int i = 0; i < 2; ++i) {            // B: 128 rows x 32 k bf16
            int idx = tid + 256 * i;
            int r = idx >> 2, kc = (idx & 3) * 8;
            *(uint4*)&Bs[r][kc] = *(const uint4*)(BT + (size_t)(n0 + r) * K + k0 + kc);
        }
        __syncthreads();
        bf16x8 af[4], bfr[4];
        #pragma unroll
        for (int mi = 0; mi < 4; ++mi)
            af[mi] = *(const bf16x8*)&As[wm * 64 + mi * 16 + l16][quad * 8];
        #pragma unroll
        for (int ni = 0; ni < 4; ++ni)
            bfr[ni] = *(const bf16x8*)&Bs[wn * 64 + ni * 16 + l16][quad * 8];
        #pragma unroll
        for (int mi = 0; mi < 4; ++mi)
            #pragma unroll
            for (int ni = 0; ni < 4; ++ni)
                acc[mi][ni] = __builtin_amdgcn_mfma_f32_16x16x32_bf16(
                    af[mi], bfr[ni], acc[mi][ni], 0, 0, 0);
        __syncthreads();
    }

    #pragma unroll
    for (int mi = 0; mi < 4; ++mi) {
        #pragma unroll
        for (int r = 0; r < 4; ++r) {
            int gm = m0 + wm * 64 + mi * 16 + quad * 4 + r;
            if (gm >= M) continue;
            int cam = gm / LTOT;
            int pix = gm - cam * LTOT;
            #pragma unroll
            for (int ni = 0; ni < 4; ++ni) {
                int gn = n0 + wn * 64 + ni * 16 + l16;
                int head = gn >> 5, ch = gn & 31;
                float v = acc[mi][ni][r] + bias[gn];
                Cb[(((size_t)(cam * 8 + head)) * LTOT + pix) * 32 + ch] = f32_to_bf16(v);
            }
        }
    }
}

// ---------------------------------------------------------------------------
// Fused query projections (A fp32 converted inline): blocks x=0,1 -> qoff;
// x=2 -> softmax(attn) -> qaw. BM=64, combined WqT [384][256].
// ---------------------------------------------------------------------------
__global__ __launch_bounds__(256) void qproj_kernel(
    const float* __restrict__ A, const unsigned short* __restrict__ WqT,
    const float* __restrict__ b_off, const float* __restrict__ b_attn,
    float* __restrict__ qoff, float* __restrict__ qaw)
{
    const int K = 256;
    __shared__ __align__(16) unsigned short As[64][40];
    __shared__ __align__(16) unsigned short Bs[128][40];

    const int tid  = threadIdx.x;
    const int wave = tid >> 6, lane = tid & 63;
    const int wm = wave >> 1, wn = wave & 1;
    const int quad = lane >> 4, l16 = lane & 15;
    const int m0 = blockIdx.y * 64, n0 = blockIdx.x * 128;
    const int is_attn = (n0 == 256);

    f32x4 acc[2][4] = {};

    for (int k0 = 0; k0 < K; k0 += 32) {
        {                                        // A: 64x32 fp32 -> bf16
            int r = tid >> 2, kc = (tid & 3) * 8;
            float4 f0 = *(const float4*)(A + (size_t)(m0 + r) * K + k0 + kc);
            float4 f1 = *(const float4*)(A + (size_t)(m0 + r) * K + k0 + kc + 4);
            uint4 o;
            o.x = f32_to_bf16(f0.x) | ((unsigned)f32_to_bf16(f0.y) << 16);
            o.y = f32_to_bf16(f0.z) | ((unsigned)f32_to_bf16(f0.w) << 16);
            o.z = f32_to_bf16(f1.x) | ((unsigned)f32_to_bf16(f1.y) << 16);
            o.w = f32_to_bf16(f1.z) | ((unsigned)f32_to_bf16(f1.w) << 16);
            *(uint4*)&As[r][kc] = o;
        }
        #pragma unroll
        for (int i = 0; i < 2; ++i) {
            int idx = tid + 256 * i;
            int r = idx >> 2, kc = (idx & 3) * 8;
            *(uint4*)&Bs[r][kc] = *(const uint4*)(WqT + (size_t)(n0 + r) * K + k0 + kc);
        }
        __syncthreads();
        bf16x8 af[2], bfr[4];
        #pragma unroll
        for (int mi = 0; mi < 2; ++mi)
            af[mi] = *(const bf16x8*)&As[wm * 32 + mi * 16 + l16][quad * 8];
        #pragma unroll
        for (int ni = 0; ni < 4; ++ni)
            bfr[ni] = *(const bf16x8*)&Bs[wn * 64 + ni * 16 + l16][quad * 8];
        #pragma unroll
        for (int mi = 0; mi < 2; ++mi)
            #pragma unroll
            for (int ni = 0; ni < 4; ++ni)
                acc[mi][ni] = __builtin_amdgcn_mfma_f32_16x16x32_bf16(
                    af[mi], bfr[ni], acc[mi][ni], 0, 0, 0);
        __syncthreads();
    }

    if (is_attn) {
        #pragma unroll
        for (int mi = 0; mi < 2; ++mi) {
            #pragma unroll
            for (int r = 0; r < 4; ++r) {
                int gm = m0 + wm * 32 + mi * 16 + quad * 4 + r;
                #pragma unroll
                for (int ni = 0; ni < 4; ++ni) {
                    int gn = wn * 64 + ni * 16 + l16;
                    float v = acc[mi][ni][r] + b_attn[gn];
                    float mx = v;
                    #pragma unroll
                    for (int s = 1; s < 16; s <<= 1)
                        mx = fmaxf(mx, __shfl_xor(mx, s, 64));
                    float e = __expf(v - mx);
                    float sum = e;
                    #pragma unroll
                    for (int s = 1; s < 16; s <<= 1)
                        sum += __shfl_xor(sum, s, 64);
                    qaw[(size_t)gm * 128 + gn] = e / sum;
                }
            }
        }
    } else {
        #pragma unroll
        for (int mi = 0; mi < 2; ++mi) {
            #pragma unroll
            for (int r = 0; r < 4; ++r) {
                int gm = m0 + wm * 32 + mi * 16 + quad * 4 + r;
                #pragma unroll
                for (int ni = 0; ni < 4; ++ni) {
                    int gn = n0 + wn * 64 + ni * 16 + l16;
                    qoff[(size_t)gm * 256 + gn] = acc[mi][ni][r] + b_off[gn];
                }
            }
        }
    }
}

// ---------------------------------------------------------------------------
// Head-partitioned deformable sampling, double-buffered corner tables:
// one __syncthreads per visible camera; table-build of cam i+1 overlaps
// the gather of cam i.
// ---------------------------------------------------------------------------
__global__ __launch_bounds__(256) void sample_kernel(
    const unsigned short* __restrict__ vb, // (6, 8, 7979, 32) bf16
    const float* __restrict__ qoff,        // (6400, 256)
    const float* __restrict__ aw,          // (6400, 128)
    const float* __restrict__ refpts,      // (6, 1, 6400, 4, 2)
    const int*   __restrict__ bev_mask,    // (6, 1, 6400, 4)
    unsigned short* __restrict__ outsum,   // (6400, 256) bf16
    float* __restrict__ visb)              // (6400)
{
    const int bid = blockIdx.x;
    const int h   = bid & 7;
    const int q0  = (bid >> 3) * 16;
    const int tid = threadIdx.x;
    const int sq  = tid >> 4;
    const int tup = tid & 15;
    const int lvl = tup >> 2;
    const int n_s = q0 + sq;
    const int tg  = (tid >> 2) & 3;
    const int cg  = tid & 3;

    __shared__ int2  s_tab[2][4][272];
    __shared__ float s_vis[NCAMS][16];
    __shared__ int   s_cnt[NCAMS];
    __shared__ int   s_nvis[16];

    if (tid < 96) {
        int cam = tid >> 4, q = tid & 15;
        const int* bm = bev_mask + ((size_t)cam * NQ + q0 + q) * 4;
        s_vis[cam][q] = ((bm[0] + bm[1] + bm[2] + bm[3]) > 0) ? 1.f : 0.f;
    }
    __syncthreads();
    if (tid < NCAMS) {
        float s = 0.f;
        #pragma unroll
        for (int q = 0; q < 16; ++q) s += s_vis[tid][q];
        s_cnt[tid] = (int)s;
    }
    if (tid >= 32 && tid < 48) {
        int q = tid - 32;
        float s = 0.f;
        #pragma unroll
        for (int cam = 0; cam < NCAMS; ++cam) s += s_vis[cam][q];
        s_nvis[q] = (int)s;
    }
    __syncthreads();

    const float my_aw = aw[(size_t)n_s * 128 + h * 16 + tup];
    const float offx  = qoff[(size_t)n_s * 256 + h * 32 + tup * 2];
    const float offy  = qoff[(size_t)n_s * 256 + h * 32 + tup * 2 + 1];
    const int Wl   = (lvl == 0) ? 100 : (lvl == 1) ? 50 : (lvl == 2) ? 25 : 13;
    const int Hl   = (lvl == 0) ? 60  : (lvl == 1) ? 30 : (lvl == 2) ? 15 : 8;
    const int base = (lvl == 0) ? 0   : (lvl == 1) ? 6000 : (lvl == 2) ? 7500 : 7875;
    const float dx = offx / (float)Wl;
    const float dy = offy / (float)Hl;
    const int tabi = sq * 17 + tup;

    // uniform visible-camera list
    int vcams[NCAMS], nvc = 0;
    #pragma unroll
    for (int k = 0; k < NCAMS; ++k)
        if (s_cnt[k] > 0) vcams[nvc++] = k;

    auto build_tab = [&](int k, int buf) {
        const size_t rbase = (((size_t)k * NQ + n_s) * 4 + lvl) * 2;
        float fx = (refpts[rbase + 0] + dx) * (float)Wl - 0.5f;
        float fy = (refpts[rbase + 1] + dy) * (float)Hl - 0.5f;
        float x0f = floorf(fx), y0f = floorf(fy);
        float lx = fx - x0f, ly = fy - y0f;
        int x0 = (int)x0f, y0 = (int)y0f;
        int x1 = x0 + 1, y1 = y0 + 1;
        float wb = my_aw * s_vis[k][sq];
        float w00 = (1.f - lx) * (1.f - ly) * wb;
        float w01 = lx * (1.f - ly) * wb;
        float w10 = (1.f - lx) * ly * wb;
        float w11 = lx * ly * wb;
        bool vx0 = (x0 >= 0) & (x0 < Wl), vx1 = (x1 >= 0) & (x1 < Wl);
        bool vy0 = (y0 >= 0) & (y0 < Hl), vy1 = (y1 >= 0) & (y1 < Hl);
        s_tab[buf][0][tabi] = make_int2((vx0 & vy0) ? (base + y0 * Wl + x0) * 64 : 0,
                                        __float_as_int((vx0 & vy0) ? w00 : 0.f));
        s_tab[buf][1][tabi] = make_int2((vx1 & vy0) ? (base + y0 * Wl + x1) * 64 : 0,
                                        __float_as_int((vx1 & vy0) ? w01 : 0.f));
        s_tab[buf][2][tabi] = make_int2((vx0 & vy1) ? (base + y1 * Wl + x0) * 64 : 0,
                                        __float_as_int((vx0 & vy1) ? w10 : 0.f));
        s_tab[buf][3][tabi] = make_int2((vx1 & vy1) ? (base + y1 * Wl + x1) * 64 : 0,
                                        __float_as_int((vx1 & vy1) ? w11 : 0.f));
    };

    float a0 = 0.f, a1 = 0.f, a2 = 0.f, a3 = 0.f;
    float a4 = 0.f, a5 = 0.f, a6 = 0.f, a7 = 0.f;

    if (nvc > 0) build_tab(vcams[0], 0);
    __syncthreads();

    int pb = 0;
    for (int i = 0; i < nvc; ++i) {
        int k = vcams[i];
        if (i + 1 < nvc) build_tab(vcams[i + 1], pb ^ 1);
        const char* vkh = (const char*)vb + (size_t)(k * 8 + h) * (LTOT * 64) + cg * 16;
        #pragma unroll
        for (int j = 0; j < 4; ++j) {
            int ti = sq * 17 + tg * 4 + j;
            #pragma unroll
            for (int corner = 0; corner < 4; ++corner) {
                int2 t = s_tab[pb][corner][ti];
                float w = __int_as_float(t.y);
                uint4 d = *(const uint4*)(vkh + t.x);
                a0 += w * __uint_as_float(d.x << 16);
                a1 += w * __uint_as_float(d.x & 0xFFFF0000u);
                a2 += w * __uint_as_float(d.y << 16);
                a3 += w * __uint_as_float(d.y & 0xFFFF0000u);
                a4 += w * __uint_as_float(d.z << 16);
                a5 += w * __uint_as_float(d.z & 0xFFFF0000u);
                a6 += w * __uint_as_float(d.w << 16);
                a7 += w * __uint_as_float(d.w & 0xFFFF0000u);
            }
        }
        __syncthreads();
        pb ^= 1;
    }

    a0 += __shfl_xor(a0, 4, 64); a0 += __shfl_xor(a0, 8, 64);
    a1 += __shfl_xor(a1, 4, 64); a1 += __shfl_xor(a1, 8, 64);
    a2 += __shfl_xor(a2, 4, 64); a2 += __shfl_xor(a2, 8, 64);
    a3 += __shfl_xor(a3, 4, 64); a3 += __shfl_xor(a3, 8, 64);
    a4 += __shfl_xor(a4, 4, 64); a4 += __shfl_xor(a4, 8, 64);
    a5 += __shfl_xor(a5, 4, 64); a5 += __shfl_xor(a5, 8, 64);
    a6 += __shfl_xor(a6, 4, 64); a6 += __shfl_xor(a6, 8, 64);
    a7 += __shfl_xor(a7, 4, 64); a7 += __shfl_xor(a7, 8, 64);

    if ((tid & 12) == 0) {
        int nv = s_nvis[sq];
        float sc = 1.f / (float)(nv > 0 ? nv : 1);
        uint4 o;
        o.x = f32_to_bf16(a0 * sc) | ((unsigned)f32_to_bf16(a1 * sc) << 16);
        o.y = f32_to_bf16(a2 * sc) | ((unsigned)f32_to_bf16(a3 * sc) << 16);
        o.z = f32_to_bf16(a4 * sc) | ((unsigned)f32_to_bf16(a5 * sc) << 16);
        o.w = f32_to_bf16(a6 * sc) | ((unsigned)f32_to_bf16(a7 * sc) << 16);
        *(uint4*)(outsum + (size_t)n_s * 256 + h * 32 + cg * 8) = o;
    }
    if (h == 0 && tid < 16) visb[q0 + tid] = (s_nvis[tid] > 0) ? 1.f : 0.f;
}

// ---------------------------------------------------------------------------
// Fused output-projection + residual + LN1. BM=32, BN=256 (full row in
// block). A=outsum bf16, BT=WoT. Writes xbuf (fp32) + xbf (bf16).
// Wave layout: wm=wave>>1 (16-row halves), wn=wave&1 (128-col halves),
// 8 n-tiles of 16x16x32 per wave.
// ---------------------------------------------------------------------------
__global__ __launch_bounds__(256) void projln1_kernel(
    const unsigned short* __restrict__ A, const unsigned short* __restrict__ BT,
    const float* __restrict__ query, const float* __restrict__ visb,
    const float* __restrict__ b_out, const float* __restrict__ g,
    const float* __restrict__ b,
    float* __restrict__ xout, unsigned short* __restrict__ xbf)
{
    const int K = 256;
    __shared__ __align__(16) unsigned short As[32][40];
    __shared__ __align__(16) unsigned short Bs[256][40];
    __shared__ float sred[2][4][4][2];
    __shared__ float ssred[2][4][4][2];
    __shared__ float s_mu[32], s_rs[32];

    const int tid  = threadIdx.x;
    const int wave = tid >> 6, lane = tid & 63;
    const int wm = wave >> 1, wn = wave & 1;
    const int quad = lane >> 4, l16 = lane & 15;
    const int m0 = blockIdx.x * 32;

    f32x4 acc[8] = {};

    for (int k0 = 0; k0 < K; k0 += 32) {
        {   // A: 32x32 shorts, 4 shorts (8B) per thread
            int r = tid >> 3, kc = (tid & 7) * 4;
            *(uint2*)&As[r][kc] = *(const uint2*)(A + (size_t)(m0 + r) * K + k0 + kc);
        }
        {   // B: row tid, 32 shorts
            const unsigned short* src = BT + (size_t)tid * K + k0;
            uint4 d0 = *(const uint4*)(src);
            uint4 d1 = *(const uint4*)(src + 8);
            uint4 d2 = *(const uint4*)(src + 16);
            uint4 d3 = *(const uint4*)(src + 24);
            *(uint4*)&Bs[tid][0]  = d0;
            *(uint4*)&Bs[tid][8]  = d1;
            *(uint4*)&Bs[tid][16] = d2;
            *(uint4*)&Bs[tid][24] = d3;
        }
        __syncthreads();
        bf16x8 af = *(const bf16x8*)&As[wm * 16 + l16][quad * 8];
        #pragma unroll
        for (int ni = 0; ni < 8; ++ni) {
            bf16x8 bfr = *(const bf16x8*)&Bs[wn * 128 + ni * 16 + l16][quad * 8];
            acc[ni] = __builtin_amdgcn_mfma_f32_16x16x32_bf16(af, bfr, acc[ni], 0, 0, 0);
        }
        __syncthreads();
    }

    // residual + stats
    float vals[8][4];
    #pragma unroll
    for (int r = 0; r < 4; ++r) {
        int gm = m0 + wm * 16 + quad * 4 + r;
        float vs = visb[gm];
        float s = 0.f, ss = 0.f;
        #pragma unroll
        for (int ni = 0; ni < 8; ++ni) {
            int gn = wn * 128 + ni * 16 + l16;
            float v = acc[ni][r] + vs * b_out[gn]
                    + query[(size_t)gm * 256 + gn] * (1.f + vs);
            vals[ni][r] = v;
            s += v; ss += v * v;
        }
        #pragma unroll
        for (int m = 1; m < 16; m <<= 1) {
            s  += __shfl_xor(s,  m, 64);
            ss += __shfl_xor(ss, m, 64);
        }
        if (l16 == 0) {
            sred[wm][quad][r][wn]  = s;
            ssred[wm][quad][r][wn] = ss;
        }
    }
    __syncthreads();
    if (tid < 32) {
        int lwm = tid >> 4, lq = (tid >> 2) & 3, lr = tid & 3;
        float s  = sred[lwm][lq][lr][0]  + sred[lwm][lq][lr][1];
        float ss = ssred[lwm][lq][lr][0] + ssred[lwm][lq][lr][1];
        float mu = s * (1.f / 256.f);
        float var = ss * (1.f / 256.f) - mu * mu;
        s_mu[tid] = mu;
        s_rs[tid] = rsqrtf(var + 1e-5f);
    }
    __syncthreads();

    #pragma unroll
    for (int r = 0; r < 4; ++r) {
        int rowl = wm * 16 + quad * 4 + r;
        int gm = m0 + rowl;
        float mu = s_mu[rowl], rs = s_rs[rowl];
        #pragma unroll
        for (int ni = 0; ni < 8; ++ni) {
            int gn = wn * 128 + ni * 16 + l16;
            float res = (vals[ni][r] - mu) * rs * g[gn] + b[gn];
            xout[(size_t)gm * 256 + gn] = res;
            xbf[(size_t)gm * 256 + gn] = f32_to_bf16(res);
        }
    }
}

// ---------------------------------------------------------------------------
// MFMA bf16 GEMM, BM=64 BN=128 BK=32, bf16 A + BT. Split-K over gridDim.z
// (each z writes its own C buffer of M*N; bias only on z==0).
// mode 0: fp32 out; mode 1: relu -> bf16 out (Cb).
// ---------------------------------------------------------------------------
__global__ __launch_bounds__(256) void gemm64_kernel(
    const unsigned short* __restrict__ A, const unsigned short* __restrict__ BT,
    const float* __restrict__ bias, float* __restrict__ C,
    unsigned short* __restrict__ Cb,
    int M, int N, int K, int mode)
{
    __shared__ __align__(16) unsigned short As[64][40];
    __shared__ __align__(16) unsigned short Bs[128][40];

    const int tid  = threadIdx.x;
    const int wave = tid >> 6, lane = tid & 63;
    const int wm = wave >> 1, wn = wave & 1;
    const int quad = lane >> 4, l16 = lane & 15;
    const int m0 = blockIdx.y * 64, n0 = blockIdx.x * 128;
    const int nz = gridDim.z;
    const int klen = K / nz;
    const int kbase = blockIdx.z * klen;

    f32x4 acc[2][4] = {};

    for (int k0 = kbase; k0 < kbase + klen; k0 += 32) {
        {
            int r = tid >> 2, kc = (tid & 3) * 8;
            int gr = m0 + r;
            uint4 d = (gr < M) ? *(const uint4*)(A + (size_t)gr * K + k0 + kc)
                               : make_uint4(0u, 0u, 0u, 0u);
            *(uint4*)&As[r][kc] = d;
        }
        #pragma unroll
        for (int i = 0; i < 2; ++i) {
            int idx = tid + 256 * i;
            int r = idx >> 2, kc = (idx & 3) * 8;
            *(uint4*)&Bs[r][kc] = *(const uint4*)(BT + (size_t)(n0 + r) * K + k0 + kc);
        }
        __syncthreads();
        bf16x8 af[2], bfr[4];
        #pragma unroll
        for (int mi = 0; mi < 2; ++mi)
            af[mi] = *(const bf16x8*)&As[wm * 32 + mi * 16 + l16][quad * 8];
        #pragma unroll
        for (int ni = 0; ni < 4; ++ni)
            bfr[ni] = *(const bf16x8*)&Bs[wn * 64 + ni * 16 + l16][quad * 8];
        #pragma unroll
        for (int mi = 0; mi < 2; ++mi)
            #pragma unroll
            for (int ni = 0; ni < 4; ++ni)
                acc[mi][ni] = __builtin_amdgcn_mfma_f32_16x16x32_bf16(
                    af[mi], bfr[ni], acc[mi][ni], 0, 0, 0);
        __syncthreads();
    }

    const float* bz = (blockIdx.z == 0) ? bias : nullptr;
    float* Cz = C ? (C + (size_t)blockIdx.z * M * N) : nullptr;

    #pragma unroll
    for (int mi = 0; mi < 2; ++mi) {
        #pragma unroll
        for (int r = 0; r < 4; ++r) {
            int gm = m0 + wm * 32 + mi * 16 + quad * 4 + r;
            if (gm >= M) continue;
            #pragma unroll
            for (int ni = 0; ni < 4; ++ni) {
                int gn = n0 + wn * 64 + ni * 16 + l16;
                float v = acc[mi][ni][r] + (bz ? bz[gn] : 0.f);
                if (mode == 1) {
                    Cb[(size_t)gm * N + gn] = f32_to_bf16(fmaxf(v, 0.f));
                } else {
                    Cz[(size_t)gm * N + gn] = v;
                }
            }
        }
    }
}

// ---------------------------------------------------------------------------
__device__ inline float block_sum_256(float v, float* red)
{
    #pragma unroll
    for (int o = 32; o > 0; o >>= 1) v += __shfl_down(v, o, 64);
    int lane = threadIdx.x & 63, w = threadIdx.x >> 6;
    if (lane == 0) red[w] = v;
    __syncthreads();
    float t = red[0] + red[1] + red[2] + red[3];
    __syncthreads();
    return t;
}

// LN2: out = LN( x + f0 + f1 )   (f0/f1 = split-K halves of the FFN output)
__global__ __launch_bounds__(256) void ln2_kernel(
    const float* __restrict__ x, const float* __restrict__ f0,
    const float* __restrict__ f1,
    const float* __restrict__ g, const float* __restrict__ b,
    float* __restrict__ out)
{
    __shared__ float red[4];
    int n = blockIdx.x, j = threadIdx.x;
    size_t idx = (size_t)n * 256 + j;
    float t = x[idx] + f0[idx] + f1[idx];
    float mu = block_sum_256(t, red) * (1.f / 256.f);
    float d = t - mu;
    float var = block_sum_256(d * d, red) * (1.f / 256.f);
    out[idx] = d * rsqrtf(var + 1e-5f) * g[j] + b[j];
}

// ---------------------------------------------------------------------------
extern "C" void kernel_launch(void* const* d_in, const int* in_sizes, int n_in,
                              void* d_out, int out_size, void* d_ws, size_t ws_size,
                              hipStream_t stream)
{
    const float* query   = (const float*)d_in[0];
    const float* value   = (const float*)d_in[2];
    const float* refpts  = (const float*)d_in[3];
    const int*   bevmask = (const int*)d_in[6];
    const float* W_value = (const float*)d_in[7];
    const float* b_value = (const float*)d_in[8];
    const float* W_off   = (const float*)d_in[9];
    const float* b_off   = (const float*)d_in[10];
    const float* W_attn  = (const float*)d_in[11];
    const float* b_attn  = (const float*)d_in[12];
    const float* W_out   = (const float*)d_in[13];
    const float* b_out   = (const float*)d_in[14];
    const float* ln1_g   = (const float*)d_in[15];
    const float* ln1_b   = (const float*)d_in[16];
    const float* W1      = (const float*)d_in[17];
    const float* b1      = (const float*)d_in[18];
    const float* W2      = (const float*)d_in[19];
    const float* b2      = (const float*)d_in[20];
    const float* ln2_g   = (const float*)d_in[21];
    const float* ln2_b   = (const float*)d_in[22];
    float* out = (float*)d_out;

    // workspace layout (byte offsets, temporal aliasing):
    //  [0)          vb bf16 24,511,488      (gemm_v -> sample)
    //  [0)          xbuf fp32 6,553,600     (projln1 -> ln2)   [vb dead]
    //  [7,000,000)  xbf bf16 3,276,800      (projln1 -> K5)    [vb dead]
    //  [11,000,000) hbf bf16 13,107,200     (K5 -> K6)         [vb dead]
    //  [25,000,000) qoff fp32 6,553,600     (qproj -> sample)
    //  [32,000,000) qaw fp32 3,276,800      (qproj -> sample)
    //  [35,300,000) outsum bf16 3,276,800   (sample -> projln1)
    //  [38,600,000) visb 25,600             (sample -> projln1)
    //  [38,700,000) wsT bf16 1,507,328      (wt -> all GEMMs)
    //  [41,000,000) ffnout fp32 2x6,553,600 (K6 -> ln2)
    char* ws = (char*)d_ws;
    unsigned short* vb     = (unsigned short*)(ws + 0);
    float*          xbuf   = (float*)(ws + 0);
    unsigned short* xbf    = (unsigned short*)(ws + 7000000);
    unsigned short* hbf    = (unsigned short*)(ws + 11000000);
    float*          qoff   = (float*)(ws + 25000000);
    float*          qaw    = (float*)(ws + 32000000);
    unsigned short* outsum = (unsigned short*)(ws + 35300000);
    float*          visb   = (float*)(ws + 38600000);
    unsigned short* wsT    = (unsigned short*)(ws + 38700000);
    float*          ffnout = (float*)(ws + 41000000);

    unsigned short* WvT = wsT;            // [256][256]
    unsigned short* WqT = wsT + 65536;    // [384][256]
    unsigned short* WoT = wsT + 163840;   // [256][256]
    unsigned short* W1T = wsT + 229376;   // [1024][256]
    unsigned short* W2T = wsT + 491520;   // [256][1024]

    const int MV = NCAMS * LTOT;  // 47874

    // P0: weight transpose+convert
    wt_kernel<<<dim3(736), 256, 0, stream>>>(
        W_value, W_off, W_attn, W_out, W1, W2, wsT);
    // K1: v = value @ W_value + b_value -> bf16 head-major (inline cvt)
    gemm_v_kernel<<<dim3(2, (MV + 127) / 128), 256, 0, stream>>>(
        value, WvT, b_value, vb, MV);
    // K2: fused qoff + attn-softmax projections (inline cvt)
    qproj_kernel<<<dim3(3, 100), 256, 0, stream>>>(
        query, WqT, b_off, b_attn, qoff, qaw);
    // K3: head-partitioned sampling (double-buffered tables)
    sample_kernel<<<dim3(3200), 256, 0, stream>>>(
        vb, qoff, qaw, refpts, bevmask, outsum, visb);
    // K4+LN1 fused: x = LN(outsum@W_out + residual algebra)
    projln1_kernel<<<dim3(200), 256, 0, stream>>>(
        outsum, WoT, query, visb, b_out, ln1_g, ln1_b, xbuf, xbf);
    // K5: hbf = bf16(relu(x @ W1 + b1))
    gemm64_kernel<<<dim3(8, 100, 1), 256, 0, stream>>>(
        xbf, W1T, b1, nullptr, hbf, NQ, DFFN, 256, 1);
    // K6: ffnout[z] = h @ W2 (+b2 on z=0), split-K x2
    gemm64_kernel<<<dim3(2, 100, 2), 256, 0, stream>>>(
        hbf, W2T, b2, ffnout, nullptr, NQ, 256, DFFN, 0);
    // LN2 -> output
    ln2_kernel<<<dim3(NQ), 256, 0, stream>>>(
        xbuf, ffnout, ffnout + (size_t)NQ * 256, ln2_g, ln2_b, out);
}